// Round 7
// baseline (209.775 us; speedup 1.0000x reference)
//
#include <hip/hip_runtime.h>
#include <cstdint>

#define V_TH 1.0f
#define RHO 0.9f
#define ADAPT 0.1f

static constexpr int B = 64, T = 8, C = 2, H = 128, W = 128;
static constexpr int H1 = 64, W1 = 64;
static constexpr int H2 = 32, W2 = 32;
static constexpr int FLAT = 32 * H2 * W2;   // 32768
static constexpr int R = B * T;             // 512

// workspace layout (bytes) — tbl (6 MB) removed: conv2 is now compute-direct
static constexpr size_t OFF_TRIP  = 0;                          // u64 [512*64*32] = 8 MB
static constexpr size_t OFF_BITS  = OFF_TRIP + 8388608;         // u32 [512*1024]  = 2 MB
static constexpr size_t OFF_PWT   = OFF_BITS + 2097152;         // f32 [32768*64]  = 8 MB
static constexpr size_t OFF_CNT   = OFF_PWT + 8388608;
static constexpr size_t OFF_PART  = OFF_CNT + 256;              // f32 [64*16*8*64] = 2 MB

// ---------------- mega1: conv1+LIF1 (direct x) | transpose | cnt ------------
// blocks: [0,1024) conv1, [1024,1536) transpose, 1536 cnt
// conv1: R1-proven configuration (measured ~41-43 us, 60 VGPR, 8 waves/SIMD):
// 6-bit float4 LDS tables per kh, depth-1 prefetch. R2 (channel-split
// occupancy), R3 (array depth-2 -> scratch), R4 (named-reg depth-2 -> VGPR
// 72 crosses the 64 cliff) all measured SLOWER. Do not touch without new
// counter evidence. The conv2 12-bit table build (192 blocks, 6 MB write)
// is REMOVED — conv2 is spike-driven from LDS weights now.
__global__ __launch_bounds__(256) void k_mega1(
    const float* __restrict__ x, const float* __restrict__ w,
    const float* __restrict__ bias, const float* __restrict__ beta,
    uint64_t* __restrict__ trip,
    const float* __restrict__ pw, float* __restrict__ pwt,
    unsigned int* __restrict__ cnt) {
  __shared__ __align__(16) float shmem[64 * 65];  // conv1: tables+weights; transpose: tile
  int bid = blockIdx.x;
  int tid = threadIdx.x;
  if (bid < 1024) {
    float4* tb = (float4*)shmem;            // [kh*4+s][64] float4 entries (3072 floats)
    float* sww = shmem + 3072;              // staged weights [288]
    for (int i = tid; i < 288; i += 256) sww[i] = w[i];
    __syncthreads();
    if (tid < 192) {                        // build tables: entry (kh, v)
      int kh = tid >> 6, v = tid & 63;
      float e[16];
#pragma unroll
      for (int c = 0; c < 16; ++c) e[c] = 0.f;
#pragma unroll
      for (int bbit = 0; bbit < 6; ++bbit) {
        if ((v >> bbit) & 1) {
          int ci = (bbit >= 3) ? 1 : 0;
          int kw = bbit - ci * 3;
          int base = ci * 9 + kh * 3 + kw;  // w[c][ci][kh][kw] = w[c*18 + base]
#pragma unroll
          for (int c = 0; c < 16; ++c) e[c] += sww[c * 18 + base];
        }
      }
#pragma unroll
      for (int s = 0; s < 4; ++s)
        tb[(kh * 4 + s) * 64 + v] =
            make_float4(e[4 * s], e[4 * s + 1], e[4 * s + 2], e[4 * s + 3]);
    }
    __syncthreads();

    int gid = bid * 256 + tid;              // (b, h1, w1)
    int h1 = (gid >> 6) & 63, b = gid >> 12;
    int lane = tid & 63;
    float bias_r[16], beta_r[16];
#pragma unroll
    for (int c = 0; c < 16; ++c) { bias_r[c] = bias[c]; beta_r[c] = beta[c]; }
    float mem[16], bth[16];
#pragma unroll
    for (int c = 0; c < 16; ++c) { mem[c] = 0.f; bth[c] = 0.f; }

    int y0 = 2 * h1 - 1;
    bool vtop = (y0 >= 0);                  // only h1==0 has an invalid top row
    const float* xb = x + (size_t)(b * T) * 2 * 16384 + 2 * lane;

    float2 cur[6];                          // [ci*3+kh]
#pragma unroll
    for (int ci = 0; ci < 2; ++ci)
#pragma unroll
      for (int kh = 0; kh < 3; ++kh) {
        int j = ci * 3 + kh;
        cur[j] = (kh == 0 && !vtop) ? make_float2(0.f, 0.f)
               : *(const float2*)(xb + ci * 16384 + (y0 + kh) * 128);
      }

    for (int t = 0; t < T; ++t) {
      int r = b * T + t;
      float2 nxt[6];
      if (t + 1 < T) {                      // prefetch next timestep's rows
        const float* xn = xb + (size_t)(t + 1) * 32768;
#pragma unroll
        for (int ci = 0; ci < 2; ++ci)
#pragma unroll
          for (int kh = 0; kh < 3; ++kh) {
            int j = ci * 3 + kh;
            nxt[j] = (kh == 0 && !vtop) ? make_float2(0.f, 0.f)
                   : *(const float2*)(xn + ci * 16384 + (y0 + kh) * 128);
          }
      }
      // build M: bit position 3*j + {0:left,1:mid,2:right}, j = ci*3+kh
      uint32_t Mc = 0, Rr = 0;
#pragma unroll
      for (int j = 0; j < 6; ++j) {
        float2 v = cur[j];
        uint32_t bm = (v.x != 0.f) ? 1u : 0u;
        uint32_t br = (v.y != 0.f) ? 1u : 0u;
        Mc |= ((bm << 1) | (br << 2)) << (3 * j);
        Rr |= br << j;
      }
      uint32_t RL = (uint32_t)__shfl((int)Rr, lane - 1, 64);  // one shuffle
      if (lane == 0) RL = 0u;
      uint32_t M = Mc | (RL & 1u) | ((RL & 2u) << 2) | ((RL & 4u) << 4)
                 | ((RL & 8u) << 6) | ((RL & 16u) << 8) | ((RL & 32u) << 10);
      int i0 = (int)((M & 7u)         | (((M >> 9) & 7u) << 3));
      int i1 = (int)(((M >> 3) & 7u)  | (((M >> 12) & 7u) << 3));
      int i2 = (int)(((M >> 6) & 7u)  | (((M >> 15) & 7u) << 3));
      float acc[16];
#pragma unroll
      for (int s = 0; s < 4; ++s) {
        float4 u0 = tb[s * 64 + i0];
        float4 u1 = tb[(4 + s) * 64 + i1];
        float4 u2 = tb[(8 + s) * 64 + i2];
        acc[4 * s + 0] = bias_r[4 * s + 0] + u0.x + u1.x + u2.x;
        acc[4 * s + 1] = bias_r[4 * s + 1] + u0.y + u1.y + u2.y;
        acc[4 * s + 2] = bias_r[4 * s + 2] + u0.z + u1.z + u2.z;
        acc[4 * s + 3] = bias_r[4 * s + 3] + u0.w + u1.w + u2.w;
      }
      uint32_t mask = 0;
#pragma unroll
      for (int c = 0; c < 16; ++c) {
        mem[c] = beta_r[c] * mem[c] + acc[c];
        float th = V_TH + bth[c];
        bool s = (mem[c] >= th);
        if (s) { mem[c] -= th; mask |= (1u << c); }
        bth[c] = RHO * bth[c] + (s ? ADAPT : 0.f);
      }
      int iL = 2 * lane - 1; if (iL < 0) iL = 0;
      uint32_t mL = __shfl((int)mask, iL, 64);
      uint32_t mC = __shfl((int)mask, 2 * lane, 64);
      uint32_t mR = __shfl((int)mask, 2 * lane + 1, 64);
      if (lane < 32) {
        uint64_t tw = (uint64_t)(lane ? mL : 0u) | ((uint64_t)mC << 16) |
                      ((uint64_t)mR << 32);
        trip[(size_t)(r * H1 + h1) * 32 + lane] = tw;
      }
      if (t + 1 < T) {
#pragma unroll
        for (int j = 0; j < 6; ++j) cur[j] = nxt[j];
      }
    }
  } else if (bid < 1536) {
    // transpose with channel permutation pos(c)=(c&3)*8+(c>>2):
    // pwt[(p*32+pos(c))*64+d] = pw[d*32768 + c*1024 + p]
    float* tile = shmem;
    int tb = bid - 1024;
    int c = tb >> 4, pt = tb & 15;
    int posc = ((c & 3) << 3) + (c >> 2);
    int p0 = pt * 64;
    int lane = tid & 63, quad = tid >> 6;
#pragma unroll
    for (int it = 0; it < 16; ++it) {
      int d = it * 4 + quad;
      tile[d * 65 + lane] = pw[(size_t)d * FLAT + c * 1024 + p0 + lane];
    }
    __syncthreads();
#pragma unroll
    for (int it = 0; it < 16; ++it) {
      int pp = it * 4 + quad;
      pwt[((size_t)((p0 + pp) * 32 + posc)) * 64 + lane] = tile[lane * 65 + pp];
    }
  } else {
    if (tid == 0) *cnt = 0u;
  }
}

// SCANROW: accumulate spiking input-channel weights for one kh row of the
// 3x3 window. Scans the 48-bit trip word in four ascending 12-bit chunks
// with a fresh group accumulator each (0.f-seeded, ascending-bit adds),
// folded left-associatively into the chain — BIT-EXACT replica of the old
// 12-bit-table entry construction + chain order.
#define SCANROW(Q, KH, R0, R1, R2, R3)                                        \
  {                                                                           \
    _Pragma("unroll")                                                         \
    for (int gp = 0; gp < 4; ++gp) {                                          \
      uint32_t m = (uint32_t)((Q) >> (12 * gp)) & 0xFFFu;                     \
      float g0 = 0.f, g1 = 0.f, g2 = 0.f, g3 = 0.f;                           \
      while (m) {                                                             \
        int i = __ffs(m) - 1; m &= m - 1;                                     \
        float4 wv = *(const float4*)(wbase + ((KH) * 48 + gp * 12 + i) * 36); \
        g0 += wv.x; g1 += wv.y; g2 += wv.z; g3 += wv.w;                       \
      }                                                                       \
      R0 += g0; R1 += g1; R2 += g2; R3 += g3;                                 \
    }                                                                         \
  }

// ---------------- stage 2: conv(16->32,s2,p1), spike-driven from LDS -------
// 8 px/wave, 8 lanes/px (li = 4 co each). Weights live in LDS (20 KB,
// [kh*48 + kw*16 + ci][co], row stride 36 floats for bank spread); per set
// trip bit: one ds_read_b128 + 4 adds. Replaces 786 MB of L2/L3 gathers
// from the 6 MB 12-bit table with spike-proportional LDS reads (69 TB/s).
// trip rows for t+1 prefetched (R5-proven).
__global__ __launch_bounds__(256) void k_conv2_lif2(
    const uint64_t* __restrict__ trip, const float* __restrict__ c2w,
    const float* __restrict__ bias, const float* __restrict__ beta,
    uint32_t* __restrict__ bits, unsigned int* __restrict__ cnt) {
  __shared__ __align__(16) float wl[144 * 36];   // 20.25 KB
  __shared__ unsigned int sc;
  int tid = threadIdx.x;
  if (tid == 0) sc = 0u;
  for (int i = tid; i < 4608; i += 256) {        // 18 iterations exactly
    int row = i >> 5, co = i & 31;               // row = kh*48 + kw*16 + ci
    int kh = row / 48, j48 = row - kh * 48;
    int kw = j48 >> 4, ci = j48 & 15;
    wl[row * 36 + co] = c2w[((co * 16 + ci) * 3 + kh) * 3 + kw];
  }
  __syncthreads();
  int lane = tid & 63;
  int li = lane & 7;
  int p8 = lane >> 3;
  int wvi = (blockIdx.x * 256 + tid) >> 6;
  int px = wvi * 8 + p8;
  int w2 = px & 31, h2 = (px >> 5) & 31, b = px >> 10;
  const float* wbase = wl + 4 * li;
  float4 b4 = *(const float4*)&bias[4 * li];
  float4 bt4 = *(const float4*)&beta[4 * li];
  float m0v = 0.f, m1v = 0.f, m2v = 0.f, m3v = 0.f;
  float t0 = 0.f, t1 = 0.f, t2 = 0.f, t3 = 0.f;
  unsigned int lc = 0;
  const uint64_t* trb = trip + ((size_t)(b * T) * 64 + 2 * h2) * 32 + w2;
  uint64_t q0 = (h2 > 0) ? trb[-32] : 0ull;
  uint64_t q1 = trb[0];
  uint64_t q2 = trb[32];
  for (int t = 0; t < T; ++t) {
    int r = b * T + t;
    uint64_t n0 = 0ull, n1 = 0ull, n2 = 0ull;
    if (t + 1 < T) {                        // prefetch next timestep's trip
      const uint64_t* trn = trb + (size_t)(t + 1) * 2048;
      n0 = (h2 > 0) ? trn[-32] : 0ull;
      n1 = trn[0];
      n2 = trn[32];
    }
    // chain order identical to the table version:
    // a = ((bias + kh0sum) + kh1sum) + kh2sum, group-major inside each kh
    float A0 = b4.x, A1 = b4.y, A2 = b4.z, A3 = b4.w;
    float B0 = 0.f, B1 = 0.f, B2 = 0.f, B3 = 0.f;
    float C0 = 0.f, C1 = 0.f, C2 = 0.f, C3 = 0.f;
    SCANROW(q0, 0, A0, A1, A2, A3)
    SCANROW(q1, 1, B0, B1, B2, B3)
    SCANROW(q2, 2, C0, C1, C2, C3)
    float a0 = (A0 + B0) + C0, a1 = (A1 + B1) + C1;
    float a2 = (A2 + B2) + C2, a3 = (A3 + B3) + C3;
    m0v = bt4.x * m0v + a0;
    m1v = bt4.y * m1v + a1;
    m2v = bt4.z * m2v + a2;
    m3v = bt4.w * m3v + a3;
    float th0 = V_TH + t0, th1 = V_TH + t1, th2 = V_TH + t2, th3 = V_TH + t3;
    bool s0 = (m0v >= th0), s1 = (m1v >= th1), s2 = (m2v >= th2), s3 = (m3v >= th3);
    if (s0) m0v -= th0;
    if (s1) m1v -= th1;
    if (s2) m2v -= th2;
    if (s3) m3v -= th3;
    t0 = RHO * t0 + (s0 ? ADAPT : 0.f);
    t1 = RHO * t1 + (s1 ? ADAPT : 0.f);
    t2 = RHO * t2 + (s2 ? ADAPT : 0.f);
    t3 = RHO * t3 + (s3 ? ADAPT : 0.f);
    unsigned long long bl0 = __ballot(s0);
    unsigned long long bl1 = __ballot(s1);
    unsigned long long bl2 = __ballot(s2);
    unsigned long long bl3 = __ballot(s3);
    if (li == 0) {
      int sh = p8 * 8;
      uint32_t m32 = ((uint32_t)(bl0 >> sh) & 0xFFu)
                   | (((uint32_t)(bl1 >> sh) & 0xFFu) << 8)
                   | (((uint32_t)(bl2 >> sh) & 0xFFu) << 16)
                   | (((uint32_t)(bl3 >> sh) & 0xFFu) << 24);
      bits[(size_t)r * 1024 + (px & 1023)] = m32;
      lc += __popc(m32);
    }
    q0 = n0; q1 = n1; q2 = n2;
  }
  if (li == 0) atomicAdd(&sc, lc);
  __syncthreads();
  if (tid == 0) atomicAdd(cnt, sc);
}

// ---------------- sparse proj GEMM: per-row scan, partials to ws ------------
// 1024 blocks x 256: block = (rt, 4 ks), wave = one ks split (16 words).
// The block's 4 ks-wave accumulators are reduced through LDS; one partial
// per block is written (64x16) -> attn's serial reduce loop shrinks 4x.
__global__ __launch_bounds__(256) void k_proj_gemm(
    const uint32_t* __restrict__ bits, const float* __restrict__ pwt,
    float* __restrict__ partial) {
  __shared__ float red[4][8][64];
  int rt = blockIdx.x >> 4;
  int blk = blockIdx.x & 15;
  int wv = threadIdx.x >> 6;
  int ks = blk * 4 + wv;
  int d = threadIdx.x & 63;
  float acc[8] = {0, 0, 0, 0, 0, 0, 0, 0};
  const uint32_t* bb = bits + (size_t)rt * 8 * 1024;
  for (int wi = 0; wi < 16; ++wi) {
    int word = ks * 16 + wi;
    const float* rowbase = pwt + ((size_t)word * 32) * 64 + d;
#pragma unroll
    for (int ri = 0; ri < 8; ++ri) {
      uint32_t m = bb[ri * 1024 + word];
      while (m) {
        int c = __ffs(m) - 1; m &= m - 1;
        acc[ri] += rowbase[c << 6];
      }
    }
  }
#pragma unroll
  for (int ri = 0; ri < 8; ++ri) red[wv][ri][d] = acc[ri];
  __syncthreads();
  if (wv == 0) {
#pragma unroll
    for (int ri = 0; ri < 8; ++ri) {
      float s = ((red[0][ri][d] + red[1][ri][d]) + red[2][ri][d]) + red[3][ri][d];
      partial[((size_t)(rt * 16 + blk) * 8 + ri) * 64 + d] = s;
    }
  }
}

// ------- reduce + MHA + mean + output LIF + classifier + sparsity ----------
__global__ __launch_bounds__(256) void k_attn_final(
    const float* __restrict__ partial, const float* __restrict__ pb,
    const float* __restrict__ wq, const float* __restrict__ wk,
    const float* __restrict__ wv, const float* __restrict__ wo,
    const float* __restrict__ clsw, const float* __restrict__ clsb,
    const unsigned int* __restrict__ cnt, float* __restrict__ out) {
  __shared__ float swq[64 * 65], swk[64 * 65], swv[64 * 65], swo[64 * 65];
  __shared__ float sp[8 * 65], sq[8 * 65], sk[8 * 65], sv[8 * 65], so2[8 * 65];
  __shared__ float satt[4][8][8];
  __shared__ float sob[64];
  int b = blockIdx.x, tid = threadIdx.x;
  for (int i = tid; i < 4096; i += 256) {
    int dd = i >> 6, e = i & 63;
    swq[dd * 65 + e] = wq[i]; swk[dd * 65 + e] = wk[i];
    swv[dd * 65 + e] = wv[i]; swo[dd * 65 + e] = wo[i];
  }
  // fused proj reduction: sp[ri][d] = pb[d] + sum_k16 partial[b][k16][ri][d]
  for (int i = tid; i < 512; i += 256) {
    int ri = i >> 6, d = i & 63;
    float s = pb[d];
    const float* p = partial + ((size_t)(b * 16) * 8 + ri) * 64 + d;
#pragma unroll
    for (int k16 = 0; k16 < 16; ++k16) s += p[(size_t)k16 * 512];
    sp[ri * 65 + d] = s;
  }
  __syncthreads();
#pragma unroll
  for (int p = 0; p < 2; ++p) {
    int idx = p * 256 + tid, t = idx >> 6, d = idx & 63;
    float qa = 0.f, ka = 0.f, va = 0.f;
    for (int e = 0; e < 64; ++e) {
      float pe = sp[t * 65 + e];
      qa += pe * swq[d * 65 + e];
      ka += pe * swk[d * 65 + e];
      va += pe * swv[d * 65 + e];
    }
    sq[t * 65 + d] = qa; sk[t * 65 + d] = ka; sv[t * 65 + d] = va;
  }
  __syncthreads();
  {
    int h = tid >> 6, q = (tid >> 3) & 7, k = tid & 7;
    float s = 0.f;
    for (int j = 0; j < 16; ++j)
      s += sq[q * 65 + h * 16 + j] * sk[k * 65 + h * 16 + j];
    satt[h][q][k] = s * 0.25f;
  }
  __syncthreads();
  if (tid < 32) {
    int h = tid >> 3, q2 = tid & 7;
    float m = -1e30f;
    for (int k2 = 0; k2 < 8; ++k2) m = fmaxf(m, satt[h][q2][k2]);
    float sum = 0.f;
    for (int k2 = 0; k2 < 8; ++k2) {
      float e = expf(satt[h][q2][k2] - m);
      satt[h][q2][k2] = e; sum += e;
    }
    float inv = 1.f / sum;
    for (int k2 = 0; k2 < 8; ++k2) satt[h][q2][k2] *= inv;
  }
  __syncthreads();
#pragma unroll
  for (int p = 0; p < 2; ++p) {
    int idx = p * 256 + tid, t = idx >> 6, d = idx & 63;
    int h = d >> 4;
    float o = 0.f;
    for (int k = 0; k < 8; ++k) o += satt[h][t][k] * sv[k * 65 + d];
    so2[t * 65 + d] = o;
  }
  __syncthreads();
  if (tid < 64) {
    float ob = 0.f;
    for (int t = 0; t < 8; ++t) ob += so2[t * 65 + tid];
    sob[tid] = ob * 0.125f;
  }
  __syncthreads();
  if (tid < 64) {
    float ctx = 0.f;
    for (int e = 0; e < 64; ++e) ctx += sob[e] * swo[tid * 65 + e];
    int spk = (ctx >= V_TH) ? 1 : 0;
    unsigned long long ball = __ballot(spk);
    if (tid < 2) {
      float lg = clsb[tid];
      for (int dd = 0; dd < 64; ++dd)
        if ((ball >> dd) & 1ull) lg += clsw[tid * 64 + dd];
      out[b * 2 + tid] = lg;
    }
    if (b == 0 && tid == 2)
      out[128] = 1.f - (float)(*cnt) / 16777216.f;
  }
}

extern "C" void kernel_launch(void* const* d_in, const int* in_sizes, int n_in,
                              void* d_out, int out_size, void* d_ws, size_t ws_size,
                              hipStream_t stream) {
  const float* x    = (const float*)d_in[0];
  const float* c1w  = (const float*)d_in[1];
  const float* c1b  = (const float*)d_in[2];
  const float* c2w  = (const float*)d_in[3];
  const float* c2b  = (const float*)d_in[4];
  const float* bt1  = (const float*)d_in[5];
  const float* bt2  = (const float*)d_in[6];
  const float* pw   = (const float*)d_in[7];
  const float* pb   = (const float*)d_in[8];
  const float* wq   = (const float*)d_in[9];
  const float* wk   = (const float*)d_in[10];
  const float* wv   = (const float*)d_in[11];
  const float* wo   = (const float*)d_in[12];
  const float* clsw = (const float*)d_in[13];
  const float* clsb = (const float*)d_in[14];
  float* out = (float*)d_out;

  uint8_t* ws = (uint8_t*)d_ws;
  uint64_t* trip  = (uint64_t*)(ws + OFF_TRIP);
  uint32_t* bits  = (uint32_t*)(ws + OFF_BITS);
  float*    pwt   = (float*)(ws + OFF_PWT);
  unsigned int* cnt = (unsigned int*)(ws + OFF_CNT);
  float*    part  = (float*)(ws + OFF_PART);

  k_mega1<<<1537, 256, 0, stream>>>(x, c1w, c1b, bt1, trip, pw, pwt, cnt);
  k_conv2_lif2<<<2048, 256, 0, stream>>>(trip, c2w, c2b, bt2, bits, cnt);
  k_proj_gemm<<<1024, 256, 0, stream>>>(bits, pwt, part);
  k_attn_final<<<64, 256, 0, stream>>>(part, pb, wq, wk, wv, wo, clsw, clsb, cnt, out);
}

// Round 8
// 205.376 us; speedup vs baseline: 1.0214x; 1.0214x over previous
//
#include <hip/hip_runtime.h>
#include <cstdint>

#define V_TH 1.0f
#define RHO 0.9f
#define ADAPT 0.1f

static constexpr int B = 64, T = 8, C = 2, H = 128, W = 128;
static constexpr int H1 = 64, W1 = 64;
static constexpr int H2 = 32, W2 = 32;
static constexpr int FLAT = 32 * H2 * W2;   // 32768
static constexpr int R = B * T;             // 512

// workspace layout (bytes) — tbl is 4 MB now (groups 0..7 only; kh2 scanned)
static constexpr size_t OFF_TRIP  = 0;                          // u64 [512*64*32] = 8 MB
static constexpr size_t OFF_BITS  = OFF_TRIP + 8388608;         // u32 [512*1024]  = 2 MB
static constexpr size_t OFF_PWT   = OFF_BITS + 2097152;         // f32 [32768*64]  = 8 MB
static constexpr size_t OFF_CNT   = OFF_PWT + 8388608;
static constexpr size_t OFF_TBL   = OFF_CNT + 256;              // f32 [8*4096*32] = 4 MB
static constexpr size_t OFF_PART  = OFF_TBL + 4194304;          // f32 [64*16*8*64] = 2 MB

// ---------------- mega1: conv1+LIF1 | transpose | cnt | table8 --------------
// blocks: [0,1024) conv1, [1024,1536) transpose, 1536 cnt, [1537,1665) table
// conv1: R1-proven configuration (measured ~41-43 us, 60 VGPR, 8 waves/SIMD).
// R2 (channel-split), R3 (array depth-2 -> scratch), R4 (named-reg depth-2 ->
// VGPR cliff) all measured SLOWER — do not touch without new counter evidence.
// Table build: groups 0..7 only (kh0,kh1); kh2 is LDS-scanned in conv2
// (R7 measured: full-LDS conv2 = LDS-pipe-bound 52.6us, full-table = L2-bound
// ~40us -> hybrid splits load across both pipes).
__global__ __launch_bounds__(256) void k_mega1(
    const float* __restrict__ x, const float* __restrict__ w,
    const float* __restrict__ bias, const float* __restrict__ beta,
    uint64_t* __restrict__ trip,
    const float* __restrict__ pw, float* __restrict__ pwt,
    const float* __restrict__ c2w, float* __restrict__ tbl,
    unsigned int* __restrict__ cnt) {
  __shared__ __align__(16) float shmem[64 * 65];  // conv1: tables+weights; transpose: tile
  int bid = blockIdx.x;
  int tid = threadIdx.x;
  if (bid < 1024) {
    float4* tb = (float4*)shmem;            // [kh*4+s][64] float4 entries (3072 floats)
    float* sww = shmem + 3072;              // staged weights [288]
    for (int i = tid; i < 288; i += 256) sww[i] = w[i];
    __syncthreads();
    if (tid < 192) {                        // build tables: entry (kh, v)
      int kh = tid >> 6, v = tid & 63;
      float e[16];
#pragma unroll
      for (int c = 0; c < 16; ++c) e[c] = 0.f;
#pragma unroll
      for (int bbit = 0; bbit < 6; ++bbit) {
        if ((v >> bbit) & 1) {
          int ci = (bbit >= 3) ? 1 : 0;
          int kw = bbit - ci * 3;
          int base = ci * 9 + kh * 3 + kw;  // w[c][ci][kh][kw] = w[c*18 + base]
#pragma unroll
          for (int c = 0; c < 16; ++c) e[c] += sww[c * 18 + base];
        }
      }
#pragma unroll
      for (int s = 0; s < 4; ++s)
        tb[(kh * 4 + s) * 64 + v] =
            make_float4(e[4 * s], e[4 * s + 1], e[4 * s + 2], e[4 * s + 3]);
    }
    __syncthreads();

    int gid = bid * 256 + tid;              // (b, h1, w1)
    int h1 = (gid >> 6) & 63, b = gid >> 12;
    int lane = tid & 63;
    float bias_r[16], beta_r[16];
#pragma unroll
    for (int c = 0; c < 16; ++c) { bias_r[c] = bias[c]; beta_r[c] = beta[c]; }
    float mem[16], bth[16];
#pragma unroll
    for (int c = 0; c < 16; ++c) { mem[c] = 0.f; bth[c] = 0.f; }

    int y0 = 2 * h1 - 1;
    bool vtop = (y0 >= 0);                  // only h1==0 has an invalid top row
    const float* xb = x + (size_t)(b * T) * 2 * 16384 + 2 * lane;

    float2 cur[6];                          // [ci*3+kh]
#pragma unroll
    for (int ci = 0; ci < 2; ++ci)
#pragma unroll
      for (int kh = 0; kh < 3; ++kh) {
        int j = ci * 3 + kh;
        cur[j] = (kh == 0 && !vtop) ? make_float2(0.f, 0.f)
               : *(const float2*)(xb + ci * 16384 + (y0 + kh) * 128);
      }

    for (int t = 0; t < T; ++t) {
      int r = b * T + t;
      float2 nxt[6];
      if (t + 1 < T) {                      // prefetch next timestep's rows
        const float* xn = xb + (size_t)(t + 1) * 32768;
#pragma unroll
        for (int ci = 0; ci < 2; ++ci)
#pragma unroll
          for (int kh = 0; kh < 3; ++kh) {
            int j = ci * 3 + kh;
            nxt[j] = (kh == 0 && !vtop) ? make_float2(0.f, 0.f)
                   : *(const float2*)(xn + ci * 16384 + (y0 + kh) * 128);
          }
      }
      // build M: bit position 3*j + {0:left,1:mid,2:right}, j = ci*3+kh
      uint32_t Mc = 0, Rr = 0;
#pragma unroll
      for (int j = 0; j < 6; ++j) {
        float2 v = cur[j];
        uint32_t bm = (v.x != 0.f) ? 1u : 0u;
        uint32_t br = (v.y != 0.f) ? 1u : 0u;
        Mc |= ((bm << 1) | (br << 2)) << (3 * j);
        Rr |= br << j;
      }
      uint32_t RL = (uint32_t)__shfl((int)Rr, lane - 1, 64);  // one shuffle
      if (lane == 0) RL = 0u;
      uint32_t M = Mc | (RL & 1u) | ((RL & 2u) << 2) | ((RL & 4u) << 4)
                 | ((RL & 8u) << 6) | ((RL & 16u) << 8) | ((RL & 32u) << 10);
      int i0 = (int)((M & 7u)         | (((M >> 9) & 7u) << 3));
      int i1 = (int)(((M >> 3) & 7u)  | (((M >> 12) & 7u) << 3));
      int i2 = (int)(((M >> 6) & 7u)  | (((M >> 15) & 7u) << 3));
      float acc[16];
#pragma unroll
      for (int s = 0; s < 4; ++s) {
        float4 u0 = tb[s * 64 + i0];
        float4 u1 = tb[(4 + s) * 64 + i1];
        float4 u2 = tb[(8 + s) * 64 + i2];
        acc[4 * s + 0] = bias_r[4 * s + 0] + u0.x + u1.x + u2.x;
        acc[4 * s + 1] = bias_r[4 * s + 1] + u0.y + u1.y + u2.y;
        acc[4 * s + 2] = bias_r[4 * s + 2] + u0.z + u1.z + u2.z;
        acc[4 * s + 3] = bias_r[4 * s + 3] + u0.w + u1.w + u2.w;
      }
      uint32_t mask = 0;
#pragma unroll
      for (int c = 0; c < 16; ++c) {
        mem[c] = beta_r[c] * mem[c] + acc[c];
        float th = V_TH + bth[c];
        bool s = (mem[c] >= th);
        if (s) { mem[c] -= th; mask |= (1u << c); }
        bth[c] = RHO * bth[c] + (s ? ADAPT : 0.f);
      }
      int iL = 2 * lane - 1; if (iL < 0) iL = 0;
      uint32_t mL = __shfl((int)mask, iL, 64);
      uint32_t mC = __shfl((int)mask, 2 * lane, 64);
      uint32_t mR = __shfl((int)mask, 2 * lane + 1, 64);
      if (lane < 32) {
        uint64_t tw = (uint64_t)(lane ? mL : 0u) | ((uint64_t)mC << 16) |
                      ((uint64_t)mR << 32);
        trip[(size_t)(r * H1 + h1) * 32 + lane] = tw;
      }
      if (t + 1 < T) {
#pragma unroll
        for (int j = 0; j < 6; ++j) cur[j] = nxt[j];
      }
    }
  } else if (bid < 1536) {
    // transpose with channel permutation pos(c)=(c&3)*8+(c>>2):
    // pwt[(p*32+pos(c))*64+d] = pw[d*32768 + c*1024 + p]
    float* tile = shmem;
    int tb = bid - 1024;
    int c = tb >> 4, pt = tb & 15;
    int posc = ((c & 3) << 3) + (c >> 2);
    int p0 = pt * 64;
    int lane = tid & 63, quad = tid >> 6;
#pragma unroll
    for (int it = 0; it < 16; ++it) {
      int d = it * 4 + quad;
      tile[d * 65 + lane] = pw[(size_t)d * FLAT + c * 1024 + p0 + lane];
    }
    __syncthreads();
#pragma unroll
    for (int it = 0; it < 16; ++it) {
      int pp = it * 4 + quad;
      pwt[((size_t)((p0 + pp) * 32 + posc)) * 64 + lane] = tile[lane * 65 + pp];
    }
  } else if (bid == 1536) {
    if (tid == 0) *cnt = 0u;
  } else {
    // conv2 12-bit table, groups 0..7 (kh0,kh1) only:
    // tbl[((kh*4+gp)*4096+v)*32+co] = sum of group's cols
    int idx = bid - 1537;               // 0..127
    int g = idx >> 4;                   // 0..7 = kh*4+gp
    int kh = g >> 2, gp = g & 3;
    int v = ((idx & 15) << 8) + tid;    // 0..4095
    float e[32];
#pragma unroll
    for (int co = 0; co < 32; ++co) e[co] = 0.f;
    for (int i = 0; i < 12; ++i) {
      if ((v >> i) & 1) {
        int j = gp * 12 + i;            // trip bit = kw*16 + ci
        int kw = j >> 4, ci = j & 15;
#pragma unroll
        for (int co = 0; co < 32; ++co)
          e[co] += c2w[((co * 16 + ci) * 3 + kh) * 3 + kw];
      }
    }
#pragma unroll
    for (int co = 0; co < 32; ++co)
      tbl[((size_t)(g * 4096 + v)) * 32 + co] = e[co];
  }
}

// ---------------- stage 2: conv(16->32,s2,p1), HYBRID ----------------------
// 8 px/wave, 8 lanes/px (li = 4 co each).
// kh0,kh1 (groups 0..7): global 12-bit table gathers (L2 pipe, 8/t).
// kh2: spike-driven scan from 6.9 KB LDS weights (LDS pipe, ~14 reads/t).
// The scan has no dependence on the gathers -> the two pipes overlap; R7
// measured each pipe alone at 52.6 (LDS) / ~40 (L2) us; hybrid targets
// max(2/3*40, 1/3*52) ~= 27-30 us. Per-group numerics identical in both
// paths (table entry == ascending-bit 0-seeded sum; fold order unchanged).
// trip rows for t+1 prefetched (R5-proven).
__global__ __launch_bounds__(256) void k_conv2_lif2(
    const uint64_t* __restrict__ trip, const float* __restrict__ tbl,
    const float* __restrict__ c2w,
    const float* __restrict__ bias, const float* __restrict__ beta,
    uint32_t* __restrict__ bits, unsigned int* __restrict__ cnt) {
  __shared__ __align__(16) float wl[48 * 36];    // kh2 weights, 6.9 KB
  __shared__ unsigned int sc;
  int tid = threadIdx.x;
  if (tid == 0) sc = 0u;
  for (int i = tid; i < 1536; i += 256) {        // 6 iterations exactly
    int row = i >> 5, co = i & 31;               // row = kw*16 + ci (bit index)
    int kw = row >> 4, ci = row & 15;
    wl[row * 36 + co] = c2w[((co * 16 + ci) * 3 + 2) * 3 + kw];
  }
  __syncthreads();
  int lane = tid & 63;
  int li = lane & 7;
  int p8 = lane >> 3;
  int wvi = (blockIdx.x * 256 + tid) >> 6;
  int px = wvi * 8 + p8;
  int w2 = px & 31, h2 = (px >> 5) & 31, b = px >> 10;
  const float* wbase = wl + 4 * li;
  float4 b4 = *(const float4*)&bias[4 * li];
  float4 bt4 = *(const float4*)&beta[4 * li];
  float m0v = 0.f, m1v = 0.f, m2v = 0.f, m3v = 0.f;
  float t0 = 0.f, t1 = 0.f, t2 = 0.f, t3 = 0.f;
  unsigned int lc = 0;
  const float4* tb4 = (const float4*)tbl;   // [g][v][li] float4, g<8
  const uint64_t* trb = trip + ((size_t)(b * T) * 64 + 2 * h2) * 32 + w2;
  uint64_t q0 = (h2 > 0) ? trb[-32] : 0ull;
  uint64_t q1 = trb[0];
  uint64_t q2 = trb[32];
  for (int t = 0; t < T; ++t) {
    int r = b * T + t;
    uint64_t n0 = 0ull, n1 = 0ull, n2 = 0ull;
    if (t + 1 < T) {                        // prefetch next timestep's trip
      const uint64_t* trn = trb + (size_t)(t + 1) * 2048;
      n0 = (h2 > 0) ? trn[-32] : 0ull;
      n1 = trn[0];
      n2 = trn[32];
    }
    uint32_t r0l = (uint32_t)q0, r0h = (uint32_t)(q0 >> 32);
    uint32_t r1l = (uint32_t)q1, r1h = (uint32_t)(q1 >> 32);
    // issue the 8 independent table gathers (kh0,kh1) — L2 pipe
    float4 v0 = tb4[(0 << 15) + ((r0l & 4095u) << 3) + li];
    float4 v1 = tb4[(1 << 15) + (((r0l >> 12) & 4095u) << 3) + li];
    float4 v2 = tb4[(2 << 15) + ((((r0l >> 24) | (r0h << 8)) & 4095u) << 3) + li];
    float4 v3 = tb4[(3 << 15) + (((r0h >> 4) & 4095u) << 3) + li];
    float4 v4 = tb4[(4 << 15) + ((r1l & 4095u) << 3) + li];
    float4 v5 = tb4[(5 << 15) + (((r1l >> 12) & 4095u) << 3) + li];
    float4 v6 = tb4[(6 << 15) + ((((r1l >> 24) | (r1h << 8)) & 4095u) << 3) + li];
    float4 v7 = tb4[(7 << 15) + (((r1h >> 4) & 4095u) << 3) + li];
    // kh2 spike-scan from LDS — runs while gathers are in flight
    float C0 = 0.f, C1 = 0.f, C2 = 0.f, C3 = 0.f;
#pragma unroll
    for (int gp = 0; gp < 4; ++gp) {
      uint32_t m = (uint32_t)(q2 >> (12 * gp)) & 0xFFFu;
      float g0 = 0.f, g1 = 0.f, g2 = 0.f, g3 = 0.f;
      while (m) {
        int i = __ffs(m) - 1; m &= m - 1;
        float4 wv = *(const float4*)(wbase + (gp * 12 + i) * 36);
        g0 += wv.x; g1 += wv.y; g2 += wv.z; g3 += wv.w;
      }
      C0 += g0; C1 += g1; C2 += g2; C3 += g3;
    }
    // kh0 chain (includes bias, preserving the established prefix order)
    float A0 = b4.x + v0.x + v1.x + v2.x + v3.x;
    float A1 = b4.y + v0.y + v1.y + v2.y + v3.y;
    float A2 = b4.z + v0.z + v1.z + v2.z + v3.z;
    float A3 = b4.w + v0.w + v1.w + v2.w + v3.w;
    // kh1 chain
    float B0 = v4.x + v5.x + v6.x + v7.x;
    float B1 = v4.y + v5.y + v6.y + v7.y;
    float B2 = v4.z + v5.z + v6.z + v7.z;
    float B3 = v4.w + v5.w + v6.w + v7.w;
    float a0 = (A0 + B0) + C0, a1 = (A1 + B1) + C1;
    float a2 = (A2 + B2) + C2, a3 = (A3 + B3) + C3;
    m0v = bt4.x * m0v + a0;
    m1v = bt4.y * m1v + a1;
    m2v = bt4.z * m2v + a2;
    m3v = bt4.w * m3v + a3;
    float th0 = V_TH + t0, th1 = V_TH + t1, th2 = V_TH + t2, th3 = V_TH + t3;
    bool s0 = (m0v >= th0), s1 = (m1v >= th1), s2 = (m2v >= th2), s3 = (m3v >= th3);
    if (s0) m0v -= th0;
    if (s1) m1v -= th1;
    if (s2) m2v -= th2;
    if (s3) m3v -= th3;
    t0 = RHO * t0 + (s0 ? ADAPT : 0.f);
    t1 = RHO * t1 + (s1 ? ADAPT : 0.f);
    t2 = RHO * t2 + (s2 ? ADAPT : 0.f);
    t3 = RHO * t3 + (s3 ? ADAPT : 0.f);
    unsigned long long bl0 = __ballot(s0);
    unsigned long long bl1 = __ballot(s1);
    unsigned long long bl2 = __ballot(s2);
    unsigned long long bl3 = __ballot(s3);
    if (li == 0) {
      int sh = p8 * 8;
      uint32_t m32 = ((uint32_t)(bl0 >> sh) & 0xFFu)
                   | (((uint32_t)(bl1 >> sh) & 0xFFu) << 8)
                   | (((uint32_t)(bl2 >> sh) & 0xFFu) << 16)
                   | (((uint32_t)(bl3 >> sh) & 0xFFu) << 24);
      bits[(size_t)r * 1024 + (px & 1023)] = m32;
      lc += __popc(m32);
    }
    q0 = n0; q1 = n1; q2 = n2;
  }
  if (li == 0) atomicAdd(&sc, lc);
  __syncthreads();
  if (tid == 0) atomicAdd(cnt, sc);
}

// ---------------- sparse proj GEMM: per-row scan, partials to ws ------------
// 1024 blocks x 256: block = (rt, 4 ks), wave = one ks split (16 words).
// The block's 4 ks-wave accumulators are reduced through LDS; one partial
// per block is written (64x16) -> attn's serial reduce loop shrinks 4x.
__global__ __launch_bounds__(256) void k_proj_gemm(
    const uint32_t* __restrict__ bits, const float* __restrict__ pwt,
    float* __restrict__ partial) {
  __shared__ float red[4][8][64];
  int rt = blockIdx.x >> 4;
  int blk = blockIdx.x & 15;
  int wv = threadIdx.x >> 6;
  int ks = blk * 4 + wv;
  int d = threadIdx.x & 63;
  float acc[8] = {0, 0, 0, 0, 0, 0, 0, 0};
  const uint32_t* bb = bits + (size_t)rt * 8 * 1024;
  for (int wi = 0; wi < 16; ++wi) {
    int word = ks * 16 + wi;
    const float* rowbase = pwt + ((size_t)word * 32) * 64 + d;
#pragma unroll
    for (int ri = 0; ri < 8; ++ri) {
      uint32_t m = bb[ri * 1024 + word];
      while (m) {
        int c = __ffs(m) - 1; m &= m - 1;
        acc[ri] += rowbase[c << 6];
      }
    }
  }
#pragma unroll
  for (int ri = 0; ri < 8; ++ri) red[wv][ri][d] = acc[ri];
  __syncthreads();
  if (wv == 0) {
#pragma unroll
    for (int ri = 0; ri < 8; ++ri) {
      float s = ((red[0][ri][d] + red[1][ri][d]) + red[2][ri][d]) + red[3][ri][d];
      partial[((size_t)(rt * 16 + blk) * 8 + ri) * 64 + d] = s;
    }
  }
}

// ------- reduce + MHA + mean + output LIF + classifier + sparsity ----------
__global__ __launch_bounds__(256) void k_attn_final(
    const float* __restrict__ partial, const float* __restrict__ pb,
    const float* __restrict__ wq, const float* __restrict__ wk,
    const float* __restrict__ wv, const float* __restrict__ wo,
    const float* __restrict__ clsw, const float* __restrict__ clsb,
    const unsigned int* __restrict__ cnt, float* __restrict__ out) {
  __shared__ float swq[64 * 65], swk[64 * 65], swv[64 * 65], swo[64 * 65];
  __shared__ float sp[8 * 65], sq[8 * 65], sk[8 * 65], sv[8 * 65], so2[8 * 65];
  __shared__ float satt[4][8][8];
  __shared__ float sob[64];
  int b = blockIdx.x, tid = threadIdx.x;
  for (int i = tid; i < 4096; i += 256) {
    int dd = i >> 6, e = i & 63;
    swq[dd * 65 + e] = wq[i]; swk[dd * 65 + e] = wk[i];
    swv[dd * 65 + e] = wv[i]; swo[dd * 65 + e] = wo[i];
  }
  // fused proj reduction: sp[ri][d] = pb[d] + sum_k16 partial[b][k16][ri][d]
  for (int i = tid; i < 512; i += 256) {
    int ri = i >> 6, d = i & 63;
    float s = pb[d];
    const float* p = partial + ((size_t)(b * 16) * 8 + ri) * 64 + d;
#pragma unroll
    for (int k16 = 0; k16 < 16; ++k16) s += p[(size_t)k16 * 512];
    sp[ri * 65 + d] = s;
  }
  __syncthreads();
#pragma unroll
  for (int p = 0; p < 2; ++p) {
    int idx = p * 256 + tid, t = idx >> 6, d = idx & 63;
    float qa = 0.f, ka = 0.f, va = 0.f;
    for (int e = 0; e < 64; ++e) {
      float pe = sp[t * 65 + e];
      qa += pe * swq[d * 65 + e];
      ka += pe * swk[d * 65 + e];
      va += pe * swv[d * 65 + e];
    }
    sq[t * 65 + d] = qa; sk[t * 65 + d] = ka; sv[t * 65 + d] = va;
  }
  __syncthreads();
  {
    int h = tid >> 6, q = (tid >> 3) & 7, k = tid & 7;
    float s = 0.f;
    for (int j = 0; j < 16; ++j)
      s += sq[q * 65 + h * 16 + j] * sk[k * 65 + h * 16 + j];
    satt[h][q][k] = s * 0.25f;
  }
  __syncthreads();
  if (tid < 32) {
    int h = tid >> 3, q2 = tid & 7;
    float m = -1e30f;
    for (int k2 = 0; k2 < 8; ++k2) m = fmaxf(m, satt[h][q2][k2]);
    float sum = 0.f;
    for (int k2 = 0; k2 < 8; ++k2) {
      float e = expf(satt[h][q2][k2] - m);
      satt[h][q2][k2] = e; sum += e;
    }
    float inv = 1.f / sum;
    for (int k2 = 0; k2 < 8; ++k2) satt[h][q2][k2] *= inv;
  }
  __syncthreads();
#pragma unroll
  for (int p = 0; p < 2; ++p) {
    int idx = p * 256 + tid, t = idx >> 6, d = idx & 63;
    int h = d >> 4;
    float o = 0.f;
    for (int k = 0; k < 8; ++k) o += satt[h][t][k] * sv[k * 65 + d];
    so2[t * 65 + d] = o;
  }
  __syncthreads();
  if (tid < 64) {
    float ob = 0.f;
    for (int t = 0; t < 8; ++t) ob += so2[t * 65 + tid];
    sob[tid] = ob * 0.125f;
  }
  __syncthreads();
  if (tid < 64) {
    float ctx = 0.f;
    for (int e = 0; e < 64; ++e) ctx += sob[e] * swo[tid * 65 + e];
    int spk = (ctx >= V_TH) ? 1 : 0;
    unsigned long long ball = __ballot(spk);
    if (tid < 2) {
      float lg = clsb[tid];
      for (int dd = 0; dd < 64; ++dd)
        if ((ball >> dd) & 1ull) lg += clsw[tid * 64 + dd];
      out[b * 2 + tid] = lg;
    }
    if (b == 0 && tid == 2)
      out[128] = 1.f - (float)(*cnt) / 16777216.f;
  }
}

extern "C" void kernel_launch(void* const* d_in, const int* in_sizes, int n_in,
                              void* d_out, int out_size, void* d_ws, size_t ws_size,
                              hipStream_t stream) {
  const float* x    = (const float*)d_in[0];
  const float* c1w  = (const float*)d_in[1];
  const float* c1b  = (const float*)d_in[2];
  const float* c2w  = (const float*)d_in[3];
  const float* c2b  = (const float*)d_in[4];
  const float* bt1  = (const float*)d_in[5];
  const float* bt2  = (const float*)d_in[6];
  const float* pw   = (const float*)d_in[7];
  const float* pb   = (const float*)d_in[8];
  const float* wq   = (const float*)d_in[9];
  const float* wk   = (const float*)d_in[10];
  const float* wv   = (const float*)d_in[11];
  const float* wo   = (const float*)d_in[12];
  const float* clsw = (const float*)d_in[13];
  const float* clsb = (const float*)d_in[14];
  float* out = (float*)d_out;

  uint8_t* ws = (uint8_t*)d_ws;
  uint64_t* trip  = (uint64_t*)(ws + OFF_TRIP);
  uint32_t* bits  = (uint32_t*)(ws + OFF_BITS);
  float*    pwt   = (float*)(ws + OFF_PWT);
  unsigned int* cnt = (unsigned int*)(ws + OFF_CNT);
  float*    tbl   = (float*)(ws + OFF_TBL);
  float*    part  = (float*)(ws + OFF_PART);

  k_mega1<<<1665, 256, 0, stream>>>(x, c1w, c1b, bt1, trip, pw, pwt, c2w, tbl, cnt);
  k_conv2_lif2<<<2048, 256, 0, stream>>>(trip, tbl, c2w, c2b, bt2, bits, cnt);
  k_proj_gemm<<<1024, 256, 0, stream>>>(bits, pwt, part);
  k_attn_final<<<64, 256, 0, stream>>>(part, pb, wq, wk, wv, wo, clsw, clsb, cnt, out);
}

// Round 9
// 199.536 us; speedup vs baseline: 1.0513x; 1.0293x over previous
//
#include <hip/hip_runtime.h>
#include <cstdint>

#define V_TH 1.0f
#define RHO 0.9f
#define ADAPT 0.1f

static constexpr int B = 64, T = 8, C = 2, H = 128, W = 128;
static constexpr int H1 = 64, W1 = 64;
static constexpr int H2 = 32, W2 = 32;
static constexpr int FLAT = 32 * H2 * W2;   // 32768
static constexpr int R = B * T;             // 512

// workspace layout (bytes) — tbl is 4 MB (groups 0..7 only; kh2 scanned)
static constexpr size_t OFF_TRIP  = 0;                          // u64 [512*64*32] = 8 MB
static constexpr size_t OFF_BITS  = OFF_TRIP + 8388608;         // u32 [512*1024]  = 2 MB
static constexpr size_t OFF_PWT   = OFF_BITS + 2097152;         // f32 [32768*64]  = 8 MB
static constexpr size_t OFF_CNT   = OFF_PWT + 8388608;
static constexpr size_t OFF_TBL   = OFF_CNT + 256;              // f32 [8*4096*32] = 4 MB
static constexpr size_t OFF_PART  = OFF_TBL + 4194304;          // f32 [64*16*8*64] = 2 MB

// ---------------- mega1: conv1+LIF1 | transpose | cnt | table8 --------------
// blocks: [0,1024) conv1, [1024,1536) transpose, 1536 cnt, [1537,1665) table
// conv1: R1-proven configuration (measured ~41-43 us, 60 VGPR, 8 waves/SIMD).
// R2 (channel-split), R3 (array depth-2 -> scratch), R4 (named-reg depth-2 ->
// VGPR cliff) all measured SLOWER — do not touch without new counter evidence.
// Table build: groups 0..7 only (kh0,kh1); kh2 is LDS-scanned in conv2
// (R8 measured: hybrid conv2 = 44.5us, FETCH 6.4MB -> table is L2-resident;
// conv2 floor is the per-t latency chain, not bandwidth).
__global__ __launch_bounds__(256) void k_mega1(
    const float* __restrict__ x, const float* __restrict__ w,
    const float* __restrict__ bias, const float* __restrict__ beta,
    uint64_t* __restrict__ trip,
    const float* __restrict__ pw, float* __restrict__ pwt,
    const float* __restrict__ c2w, float* __restrict__ tbl,
    unsigned int* __restrict__ cnt) {
  __shared__ __align__(16) float shmem[64 * 65];  // conv1: tables+weights; transpose: tile
  int bid = blockIdx.x;
  int tid = threadIdx.x;
  if (bid < 1024) {
    float4* tb = (float4*)shmem;            // [kh*4+s][64] float4 entries (3072 floats)
    float* sww = shmem + 3072;              // staged weights [288]
    for (int i = tid; i < 288; i += 256) sww[i] = w[i];
    __syncthreads();
    if (tid < 192) {                        // build tables: entry (kh, v)
      int kh = tid >> 6, v = tid & 63;
      float e[16];
#pragma unroll
      for (int c = 0; c < 16; ++c) e[c] = 0.f;
#pragma unroll
      for (int bbit = 0; bbit < 6; ++bbit) {
        if ((v >> bbit) & 1) {
          int ci = (bbit >= 3) ? 1 : 0;
          int kw = bbit - ci * 3;
          int base = ci * 9 + kh * 3 + kw;  // w[c][ci][kh][kw] = w[c*18 + base]
#pragma unroll
          for (int c = 0; c < 16; ++c) e[c] += sww[c * 18 + base];
        }
      }
#pragma unroll
      for (int s = 0; s < 4; ++s)
        tb[(kh * 4 + s) * 64 + v] =
            make_float4(e[4 * s], e[4 * s + 1], e[4 * s + 2], e[4 * s + 3]);
    }
    __syncthreads();

    int gid = bid * 256 + tid;              // (b, h1, w1)
    int h1 = (gid >> 6) & 63, b = gid >> 12;
    int lane = tid & 63;
    float bias_r[16], beta_r[16];
#pragma unroll
    for (int c = 0; c < 16; ++c) { bias_r[c] = bias[c]; beta_r[c] = beta[c]; }
    float mem[16], bth[16];
#pragma unroll
    for (int c = 0; c < 16; ++c) { mem[c] = 0.f; bth[c] = 0.f; }

    int y0 = 2 * h1 - 1;
    bool vtop = (y0 >= 0);                  // only h1==0 has an invalid top row
    const float* xb = x + (size_t)(b * T) * 2 * 16384 + 2 * lane;

    float2 cur[6];                          // [ci*3+kh]
#pragma unroll
    for (int ci = 0; ci < 2; ++ci)
#pragma unroll
      for (int kh = 0; kh < 3; ++kh) {
        int j = ci * 3 + kh;
        cur[j] = (kh == 0 && !vtop) ? make_float2(0.f, 0.f)
               : *(const float2*)(xb + ci * 16384 + (y0 + kh) * 128);
      }

    for (int t = 0; t < T; ++t) {
      int r = b * T + t;
      float2 nxt[6];
      if (t + 1 < T) {                      // prefetch next timestep's rows
        const float* xn = xb + (size_t)(t + 1) * 32768;
#pragma unroll
        for (int ci = 0; ci < 2; ++ci)
#pragma unroll
          for (int kh = 0; kh < 3; ++kh) {
            int j = ci * 3 + kh;
            nxt[j] = (kh == 0 && !vtop) ? make_float2(0.f, 0.f)
                   : *(const float2*)(xn + ci * 16384 + (y0 + kh) * 128);
          }
      }
      // build M: bit position 3*j + {0:left,1:mid,2:right}, j = ci*3+kh
      uint32_t Mc = 0, Rr = 0;
#pragma unroll
      for (int j = 0; j < 6; ++j) {
        float2 v = cur[j];
        uint32_t bm = (v.x != 0.f) ? 1u : 0u;
        uint32_t br = (v.y != 0.f) ? 1u : 0u;
        Mc |= ((bm << 1) | (br << 2)) << (3 * j);
        Rr |= br << j;
      }
      uint32_t RL = (uint32_t)__shfl((int)Rr, lane - 1, 64);  // one shuffle
      if (lane == 0) RL = 0u;
      uint32_t M = Mc | (RL & 1u) | ((RL & 2u) << 2) | ((RL & 4u) << 4)
                 | ((RL & 8u) << 6) | ((RL & 16u) << 8) | ((RL & 32u) << 10);
      int i0 = (int)((M & 7u)         | (((M >> 9) & 7u) << 3));
      int i1 = (int)(((M >> 3) & 7u)  | (((M >> 12) & 7u) << 3));
      int i2 = (int)(((M >> 6) & 7u)  | (((M >> 15) & 7u) << 3));
      float acc[16];
#pragma unroll
      for (int s = 0; s < 4; ++s) {
        float4 u0 = tb[s * 64 + i0];
        float4 u1 = tb[(4 + s) * 64 + i1];
        float4 u2 = tb[(8 + s) * 64 + i2];
        acc[4 * s + 0] = bias_r[4 * s + 0] + u0.x + u1.x + u2.x;
        acc[4 * s + 1] = bias_r[4 * s + 1] + u0.y + u1.y + u2.y;
        acc[4 * s + 2] = bias_r[4 * s + 2] + u0.z + u1.z + u2.z;
        acc[4 * s + 3] = bias_r[4 * s + 3] + u0.w + u1.w + u2.w;
      }
      uint32_t mask = 0;
#pragma unroll
      for (int c = 0; c < 16; ++c) {
        mem[c] = beta_r[c] * mem[c] + acc[c];
        float th = V_TH + bth[c];
        bool s = (mem[c] >= th);
        if (s) { mem[c] -= th; mask |= (1u << c); }
        bth[c] = RHO * bth[c] + (s ? ADAPT : 0.f);
      }
      int iL = 2 * lane - 1; if (iL < 0) iL = 0;
      uint32_t mL = __shfl((int)mask, iL, 64);
      uint32_t mC = __shfl((int)mask, 2 * lane, 64);
      uint32_t mR = __shfl((int)mask, 2 * lane + 1, 64);
      if (lane < 32) {
        uint64_t tw = (uint64_t)(lane ? mL : 0u) | ((uint64_t)mC << 16) |
                      ((uint64_t)mR << 32);
        trip[(size_t)(r * H1 + h1) * 32 + lane] = tw;
      }
      if (t + 1 < T) {
#pragma unroll
        for (int j = 0; j < 6; ++j) cur[j] = nxt[j];
      }
    }
  } else if (bid < 1536) {
    // transpose with channel permutation pos(c)=(c&3)*8+(c>>2):
    // pwt[(p*32+pos(c))*64+d] = pw[d*32768 + c*1024 + p]
    float* tile = shmem;
    int tb = bid - 1024;
    int c = tb >> 4, pt = tb & 15;
    int posc = ((c & 3) << 3) + (c >> 2);
    int p0 = pt * 64;
    int lane = tid & 63, quad = tid >> 6;
#pragma unroll
    for (int it = 0; it < 16; ++it) {
      int d = it * 4 + quad;
      tile[d * 65 + lane] = pw[(size_t)d * FLAT + c * 1024 + p0 + lane];
    }
    __syncthreads();
#pragma unroll
    for (int it = 0; it < 16; ++it) {
      int pp = it * 4 + quad;
      pwt[((size_t)((p0 + pp) * 32 + posc)) * 64 + lane] = tile[lane * 65 + pp];
    }
  } else if (bid == 1536) {
    if (tid == 0) *cnt = 0u;
  } else {
    // conv2 12-bit table, groups 0..7 (kh0,kh1) only:
    // tbl[((kh*4+gp)*4096+v)*32+co] = sum of group's cols
    int idx = bid - 1537;               // 0..127
    int g = idx >> 4;                   // 0..7 = kh*4+gp
    int kh = g >> 2, gp = g & 3;
    int v = ((idx & 15) << 8) + tid;    // 0..4095
    float e[32];
#pragma unroll
    for (int co = 0; co < 32; ++co) e[co] = 0.f;
    for (int i = 0; i < 12; ++i) {
      if ((v >> i) & 1) {
        int j = gp * 12 + i;            // trip bit = kw*16 + ci
        int kw = j >> 4, ci = j & 15;
#pragma unroll
        for (int co = 0; co < 32; ++co)
          e[co] += c2w[((co * 16 + ci) * 3 + kh) * 3 + kw];
      }
    }
#pragma unroll
    for (int co = 0; co < 32; ++co)
      tbl[((size_t)(g * 4096 + v)) * 32 + co] = e[co];
  }
}

// ---------------- stage 2: conv(16->32,s2,p1), HYBRID ----------------------
// 8 px/wave, 8 lanes/px (li = 4 co each).
// kh0,kh1 (groups 0..7): global 12-bit table gathers (L2 pipe, 8/t).
// kh2: spike-driven scan from 6.9 KB LDS weights (LDS pipe, ~14 reads/t).
// R8 measured 44.5us (vs 52.6 full-LDS); FETCH 6.4MB -> table L2-resident;
// remaining floor is the per-t dependency chain. trip t+1 prefetched.
__global__ __launch_bounds__(256) void k_conv2_lif2(
    const uint64_t* __restrict__ trip, const float* __restrict__ tbl,
    const float* __restrict__ c2w,
    const float* __restrict__ bias, const float* __restrict__ beta,
    uint32_t* __restrict__ bits, unsigned int* __restrict__ cnt) {
  __shared__ __align__(16) float wl[48 * 36];    // kh2 weights, 6.9 KB
  __shared__ unsigned int sc;
  int tid = threadIdx.x;
  if (tid == 0) sc = 0u;
  for (int i = tid; i < 1536; i += 256) {        // 6 iterations exactly
    int row = i >> 5, co = i & 31;               // row = kw*16 + ci (bit index)
    int kw = row >> 4, ci = row & 15;
    wl[row * 36 + co] = c2w[((co * 16 + ci) * 3 + 2) * 3 + kw];
  }
  __syncthreads();
  int lane = tid & 63;
  int li = lane & 7;
  int p8 = lane >> 3;
  int wvi = (blockIdx.x * 256 + tid) >> 6;
  int px = wvi * 8 + p8;
  int w2 = px & 31, h2 = (px >> 5) & 31, b = px >> 10;
  const float* wbase = wl + 4 * li;
  float4 b4 = *(const float4*)&bias[4 * li];
  float4 bt4 = *(const float4*)&beta[4 * li];
  float m0v = 0.f, m1v = 0.f, m2v = 0.f, m3v = 0.f;
  float t0 = 0.f, t1 = 0.f, t2 = 0.f, t3 = 0.f;
  unsigned int lc = 0;
  const float4* tb4 = (const float4*)tbl;   // [g][v][li] float4, g<8
  const uint64_t* trb = trip + ((size_t)(b * T) * 64 + 2 * h2) * 32 + w2;
  uint64_t q0 = (h2 > 0) ? trb[-32] : 0ull;
  uint64_t q1 = trb[0];
  uint64_t q2 = trb[32];
  for (int t = 0; t < T; ++t) {
    int r = b * T + t;
    uint64_t n0 = 0ull, n1 = 0ull, n2 = 0ull;
    if (t + 1 < T) {                        // prefetch next timestep's trip
      const uint64_t* trn = trb + (size_t)(t + 1) * 2048;
      n0 = (h2 > 0) ? trn[-32] : 0ull;
      n1 = trn[0];
      n2 = trn[32];
    }
    uint32_t r0l = (uint32_t)q0, r0h = (uint32_t)(q0 >> 32);
    uint32_t r1l = (uint32_t)q1, r1h = (uint32_t)(q1 >> 32);
    // issue the 8 independent table gathers (kh0,kh1) — L2 pipe
    float4 v0 = tb4[(0 << 15) + ((r0l & 4095u) << 3) + li];
    float4 v1 = tb4[(1 << 15) + (((r0l >> 12) & 4095u) << 3) + li];
    float4 v2 = tb4[(2 << 15) + ((((r0l >> 24) | (r0h << 8)) & 4095u) << 3) + li];
    float4 v3 = tb4[(3 << 15) + (((r0h >> 4) & 4095u) << 3) + li];
    float4 v4 = tb4[(4 << 15) + ((r1l & 4095u) << 3) + li];
    float4 v5 = tb4[(5 << 15) + (((r1l >> 12) & 4095u) << 3) + li];
    float4 v6 = tb4[(6 << 15) + ((((r1l >> 24) | (r1h << 8)) & 4095u) << 3) + li];
    float4 v7 = tb4[(7 << 15) + (((r1h >> 4) & 4095u) << 3) + li];
    // kh2 spike-scan from LDS — runs while gathers are in flight
    float C0 = 0.f, C1 = 0.f, C2 = 0.f, C3 = 0.f;
#pragma unroll
    for (int gp = 0; gp < 4; ++gp) {
      uint32_t m = (uint32_t)(q2 >> (12 * gp)) & 0xFFFu;
      float g0 = 0.f, g1 = 0.f, g2 = 0.f, g3 = 0.f;
      while (m) {
        int i = __ffs(m) - 1; m &= m - 1;
        float4 wv = *(const float4*)(wbase + (gp * 12 + i) * 36);
        g0 += wv.x; g1 += wv.y; g2 += wv.z; g3 += wv.w;
      }
      C0 += g0; C1 += g1; C2 += g2; C3 += g3;
    }
    // kh0 chain (includes bias, preserving the established prefix order)
    float A0 = b4.x + v0.x + v1.x + v2.x + v3.x;
    float A1 = b4.y + v0.y + v1.y + v2.y + v3.y;
    float A2 = b4.z + v0.z + v1.z + v2.z + v3.z;
    float A3 = b4.w + v0.w + v1.w + v2.w + v3.w;
    // kh1 chain
    float B0 = v4.x + v5.x + v6.x + v7.x;
    float B1 = v4.y + v5.y + v6.y + v7.y;
    float B2 = v4.z + v5.z + v6.z + v7.z;
    float B3 = v4.w + v5.w + v6.w + v7.w;
    float a0 = (A0 + B0) + C0, a1 = (A1 + B1) + C1;
    float a2 = (A2 + B2) + C2, a3 = (A3 + B3) + C3;
    m0v = bt4.x * m0v + a0;
    m1v = bt4.y * m1v + a1;
    m2v = bt4.z * m2v + a2;
    m3v = bt4.w * m3v + a3;
    float th0 = V_TH + t0, th1 = V_TH + t1, th2 = V_TH + t2, th3 = V_TH + t3;
    bool s0 = (m0v >= th0), s1 = (m1v >= th1), s2 = (m2v >= th2), s3 = (m3v >= th3);
    if (s0) m0v -= th0;
    if (s1) m1v -= th1;
    if (s2) m2v -= th2;
    if (s3) m3v -= th3;
    t0 = RHO * t0 + (s0 ? ADAPT : 0.f);
    t1 = RHO * t1 + (s1 ? ADAPT : 0.f);
    t2 = RHO * t2 + (s2 ? ADAPT : 0.f);
    t3 = RHO * t3 + (s3 ? ADAPT : 0.f);
    unsigned long long bl0 = __ballot(s0);
    unsigned long long bl1 = __ballot(s1);
    unsigned long long bl2 = __ballot(s2);
    unsigned long long bl3 = __ballot(s3);
    if (li == 0) {
      int sh = p8 * 8;
      uint32_t m32 = ((uint32_t)(bl0 >> sh) & 0xFFu)
                   | (((uint32_t)(bl1 >> sh) & 0xFFu) << 8)
                   | (((uint32_t)(bl2 >> sh) & 0xFFu) << 16)
                   | (((uint32_t)(bl3 >> sh) & 0xFFu) << 24);
      bits[(size_t)r * 1024 + (px & 1023)] = m32;
      lc += __popc(m32);
    }
    q0 = n0; q1 = n1; q2 = n2;
  }
  if (li == 0) atomicAdd(&sc, lc);
  __syncthreads();
  if (tid == 0) atomicAdd(cnt, sc);
}

// ---------------- sparse proj GEMM: 8-way interleaved row scan --------------
// 1024 blocks x 256: block = (rt, 4 ks), wave = one ks split (16 words).
// The 8 ri row-masks of each word are scanned CONCURRENTLY (named m0..m7 /
// a0..a7): 8 independent load->add chains (8x MLP) and iteration count =
// max popcount instead of sum (~8 vs ~20). Masks are wave-uniform -> guards
// are uniform branches, no divergence. Next word's masks prefetched.
// BIT-EXACT: each a_ri's adds keep word order + ascending-bit order; only
// cross-accumulator timing changes. Block's 4 ks-waves reduced via LDS
// (one 64x16 partial per block -> attn reduce stays k16).
__global__ __launch_bounds__(256) void k_proj_gemm(
    const uint32_t* __restrict__ bits, const float* __restrict__ pwt,
    float* __restrict__ partial) {
  __shared__ float red[4][8][64];
  int rt = blockIdx.x >> 4;
  int blk = blockIdx.x & 15;
  int wv = threadIdx.x >> 6;
  int ks = blk * 4 + wv;
  int d = threadIdx.x & 63;
  float a0 = 0.f, a1 = 0.f, a2 = 0.f, a3 = 0.f;
  float a4 = 0.f, a5 = 0.f, a6 = 0.f, a7 = 0.f;
  const uint32_t* bb = bits + (size_t)rt * 8 * 1024;
  int word0 = ks * 16;
  uint32_t m0 = bb[word0],          m1 = bb[1024 + word0];
  uint32_t m2 = bb[2048 + word0],   m3 = bb[3072 + word0];
  uint32_t m4 = bb[4096 + word0],   m5 = bb[5120 + word0];
  uint32_t m6 = bb[6144 + word0],   m7 = bb[7168 + word0];
  for (int wi = 0; wi < 16; ++wi) {
    int word = word0 + wi;
    const float* rowbase = pwt + ((size_t)word * 32) * 64 + d;
    uint32_t n0 = 0u, n1 = 0u, n2 = 0u, n3 = 0u;
    uint32_t n4 = 0u, n5 = 0u, n6 = 0u, n7 = 0u;
    if (wi + 1 < 16) {                       // prefetch next word's masks
      int wn = word + 1;
      n0 = bb[wn];          n1 = bb[1024 + wn];
      n2 = bb[2048 + wn];   n3 = bb[3072 + wn];
      n4 = bb[4096 + wn];   n5 = bb[5120 + wn];
      n6 = bb[6144 + wn];   n7 = bb[7168 + wn];
    }
    while (m0 | m1 | m2 | m3 | m4 | m5 | m6 | m7) {
      if (m0) { int c = __ffs(m0) - 1; m0 &= m0 - 1; a0 += rowbase[c << 6]; }
      if (m1) { int c = __ffs(m1) - 1; m1 &= m1 - 1; a1 += rowbase[c << 6]; }
      if (m2) { int c = __ffs(m2) - 1; m2 &= m2 - 1; a2 += rowbase[c << 6]; }
      if (m3) { int c = __ffs(m3) - 1; m3 &= m3 - 1; a3 += rowbase[c << 6]; }
      if (m4) { int c = __ffs(m4) - 1; m4 &= m4 - 1; a4 += rowbase[c << 6]; }
      if (m5) { int c = __ffs(m5) - 1; m5 &= m5 - 1; a5 += rowbase[c << 6]; }
      if (m6) { int c = __ffs(m6) - 1; m6 &= m6 - 1; a6 += rowbase[c << 6]; }
      if (m7) { int c = __ffs(m7) - 1; m7 &= m7 - 1; a7 += rowbase[c << 6]; }
    }
    m0 = n0; m1 = n1; m2 = n2; m3 = n3;
    m4 = n4; m5 = n5; m6 = n6; m7 = n7;
  }
  red[wv][0][d] = a0; red[wv][1][d] = a1;
  red[wv][2][d] = a2; red[wv][3][d] = a3;
  red[wv][4][d] = a4; red[wv][5][d] = a5;
  red[wv][6][d] = a6; red[wv][7][d] = a7;
  __syncthreads();
  if (wv == 0) {
#pragma unroll
    for (int ri = 0; ri < 8; ++ri) {
      float s = ((red[0][ri][d] + red[1][ri][d]) + red[2][ri][d]) + red[3][ri][d];
      partial[((size_t)(rt * 16 + blk) * 8 + ri) * 64 + d] = s;
    }
  }
}

// ------- reduce + MHA + mean + output LIF + classifier + sparsity ----------
__global__ __launch_bounds__(256) void k_attn_final(
    const float* __restrict__ partial, const float* __restrict__ pb,
    const float* __restrict__ wq, const float* __restrict__ wk,
    const float* __restrict__ wv, const float* __restrict__ wo,
    const float* __restrict__ clsw, const float* __restrict__ clsb,
    const unsigned int* __restrict__ cnt, float* __restrict__ out) {
  __shared__ float swq[64 * 65], swk[64 * 65], swv[64 * 65], swo[64 * 65];
  __shared__ float sp[8 * 65], sq[8 * 65], sk[8 * 65], sv[8 * 65], so2[8 * 65];
  __shared__ float satt[4][8][8];
  __shared__ float sob[64];
  int b = blockIdx.x, tid = threadIdx.x;
  for (int i = tid; i < 4096; i += 256) {
    int dd = i >> 6, e = i & 63;
    swq[dd * 65 + e] = wq[i]; swk[dd * 65 + e] = wk[i];
    swv[dd * 65 + e] = wv[i]; swo[dd * 65 + e] = wo[i];
  }
  // fused proj reduction: sp[ri][d] = pb[d] + sum_k16 partial[b][k16][ri][d]
  for (int i = tid; i < 512; i += 256) {
    int ri = i >> 6, d = i & 63;
    float s = pb[d];
    const float* p = partial + ((size_t)(b * 16) * 8 + ri) * 64 + d;
#pragma unroll
    for (int k16 = 0; k16 < 16; ++k16) s += p[(size_t)k16 * 512];
    sp[ri * 65 + d] = s;
  }
  __syncthreads();
#pragma unroll
  for (int p = 0; p < 2; ++p) {
    int idx = p * 256 + tid, t = idx >> 6, d = idx & 63;
    float qa = 0.f, ka = 0.f, va = 0.f;
    for (int e = 0; e < 64; ++e) {
      float pe = sp[t * 65 + e];
      qa += pe * swq[d * 65 + e];
      ka += pe * swk[d * 65 + e];
      va += pe * swv[d * 65 + e];
    }
    sq[t * 65 + d] = qa; sk[t * 65 + d] = ka; sv[t * 65 + d] = va;
  }
  __syncthreads();
  {
    int h = tid >> 6, q = (tid >> 3) & 7, k = tid & 7;
    float s = 0.f;
    for (int j = 0; j < 16; ++j)
      s += sq[q * 65 + h * 16 + j] * sk[k * 65 + h * 16 + j];
    satt[h][q][k] = s * 0.25f;
  }
  __syncthreads();
  if (tid < 32) {
    int h = tid >> 3, q2 = tid & 7;
    float m = -1e30f;
    for (int k2 = 0; k2 < 8; ++k2) m = fmaxf(m, satt[h][q2][k2]);
    float sum = 0.f;
    for (int k2 = 0; k2 < 8; ++k2) {
      float e = expf(satt[h][q2][k2] - m);
      satt[h][q2][k2] = e; sum += e;
    }
    float inv = 1.f / sum;
    for (int k2 = 0; k2 < 8; ++k2) satt[h][q2][k2] *= inv;
  }
  __syncthreads();
#pragma unroll
  for (int p = 0; p < 2; ++p) {
    int idx = p * 256 + tid, t = idx >> 6, d = idx & 63;
    int h = d >> 4;
    float o = 0.f;
    for (int k = 0; k < 8; ++k) o += satt[h][t][k] * sv[k * 65 + d];
    so2[t * 65 + d] = o;
  }
  __syncthreads();
  if (tid < 64) {
    float ob = 0.f;
    for (int t = 0; t < 8; ++t) ob += so2[t * 65 + tid];
    sob[tid] = ob * 0.125f;
  }
  __syncthreads();
  if (tid < 64) {
    float ctx = 0.f;
    for (int e = 0; e < 64; ++e) ctx += sob[e] * swo[tid * 65 + e];
    int spk = (ctx >= V_TH) ? 1 : 0;
    unsigned long long ball = __ballot(spk);
    if (tid < 2) {
      float lg = clsb[tid];
      for (int dd = 0; dd < 64; ++dd)
        if ((ball >> dd) & 1ull) lg += clsw[tid * 64 + dd];
      out[b * 2 + tid] = lg;
    }
    if (b == 0 && tid == 2)
      out[128] = 1.f - (float)(*cnt) / 16777216.f;
  }
}

extern "C" void kernel_launch(void* const* d_in, const int* in_sizes, int n_in,
                              void* d_out, int out_size, void* d_ws, size_t ws_size,
                              hipStream_t stream) {
  const float* x    = (const float*)d_in[0];
  const float* c1w  = (const float*)d_in[1];
  const float* c1b  = (const float*)d_in[2];
  const float* c2w  = (const float*)d_in[3];
  const float* c2b  = (const float*)d_in[4];
  const float* bt1  = (const float*)d_in[5];
  const float* bt2  = (const float*)d_in[6];
  const float* pw   = (const float*)d_in[7];
  const float* pb   = (const float*)d_in[8];
  const float* wq   = (const float*)d_in[9];
  const float* wk   = (const float*)d_in[10];
  const float* wv   = (const float*)d_in[11];
  const float* wo   = (const float*)d_in[12];
  const float* clsw = (const float*)d_in[13];
  const float* clsb = (const float*)d_in[14];
  float* out = (float*)d_out;

  uint8_t* ws = (uint8_t*)d_ws;
  uint64_t* trip  = (uint64_t*)(ws + OFF_TRIP);
  uint32_t* bits  = (uint32_t*)(ws + OFF_BITS);
  float*    pwt   = (float*)(ws + OFF_PWT);
  unsigned int* cnt = (unsigned int*)(ws + OFF_CNT);
  float*    tbl   = (float*)(ws + OFF_TBL);
  float*    part  = (float*)(ws + OFF_PART);

  k_mega1<<<1665, 256, 0, stream>>>(x, c1w, c1b, bt1, trip, pw, pwt, c2w, tbl, cnt);
  k_conv2_lif2<<<2048, 256, 0, stream>>>(trip, tbl, c2w, c2b, bt2, bits, cnt);
  k_proj_gemm<<<1024, 256, 0, stream>>>(bits, pwt, part);
  k_attn_final<<<64, 256, 0, stream>>>(part, pb, wq, wk, wv, wo, clsw, clsb, cnt, out);
}

// Round 10
// 197.293 us; speedup vs baseline: 1.0633x; 1.0114x over previous
//
#include <hip/hip_runtime.h>
#include <cstdint>

#define V_TH 1.0f
#define RHO 0.9f
#define ADAPT 0.1f

static constexpr int B = 64, T = 8, C = 2, H = 128, W = 128;
static constexpr int H1 = 64, W1 = 64;
static constexpr int H2 = 32, W2 = 32;
static constexpr int FLAT = 32 * H2 * W2;   // 32768
static constexpr int R = B * T;             // 512

// workspace layout (bytes) — tbl is 4 MB (groups 0..7 only; kh2 scanned)
static constexpr size_t OFF_TRIP  = 0;                          // u64 [512*64*32] = 8 MB
static constexpr size_t OFF_BITS  = OFF_TRIP + 8388608;         // u32 [512*1024]  = 2 MB
static constexpr size_t OFF_PWT   = OFF_BITS + 2097152;         // f32 [32768*64]  = 8 MB
static constexpr size_t OFF_CNT   = OFF_PWT + 8388608;
static constexpr size_t OFF_TBL   = OFF_CNT + 256;              // f32 [8*4096*32] = 4 MB
static constexpr size_t OFF_PART  = OFF_TBL + 4194304;          // f32 [64*16*8*64] = 2 MB

// ---------------- mega1: conv1+LIF1 | transpose | cnt | table8 --------------
// blocks: [0,1024) conv1, [1024,1536) transpose, 1536 cnt, [1537,1665) table
// conv1: R1-proven configuration (measured ~41-43 us, 60 VGPR, 8 waves/SIMD).
// R2 (channel-split), R3 (array depth-2 -> scratch), R4 (named-reg depth-2 ->
// VGPR cliff) all measured SLOWER — do not touch without new counter evidence.
// Table build: groups 0..7 only (kh0,kh1); kh2 is LDS-scanned in conv2.
__global__ __launch_bounds__(256) void k_mega1(
    const float* __restrict__ x, const float* __restrict__ w,
    const float* __restrict__ bias, const float* __restrict__ beta,
    uint64_t* __restrict__ trip,
    const float* __restrict__ pw, float* __restrict__ pwt,
    const float* __restrict__ c2w, float* __restrict__ tbl,
    unsigned int* __restrict__ cnt) {
  __shared__ __align__(16) float shmem[64 * 65];  // conv1: tables+weights; transpose: tile
  int bid = blockIdx.x;
  int tid = threadIdx.x;
  if (bid < 1024) {
    float4* tb = (float4*)shmem;            // [kh*4+s][64] float4 entries (3072 floats)
    float* sww = shmem + 3072;              // staged weights [288]
    for (int i = tid; i < 288; i += 256) sww[i] = w[i];
    __syncthreads();
    if (tid < 192) {                        // build tables: entry (kh, v)
      int kh = tid >> 6, v = tid & 63;
      float e[16];
#pragma unroll
      for (int c = 0; c < 16; ++c) e[c] = 0.f;
#pragma unroll
      for (int bbit = 0; bbit < 6; ++bbit) {
        if ((v >> bbit) & 1) {
          int ci = (bbit >= 3) ? 1 : 0;
          int kw = bbit - ci * 3;
          int base = ci * 9 + kh * 3 + kw;  // w[c][ci][kh][kw] = w[c*18 + base]
#pragma unroll
          for (int c = 0; c < 16; ++c) e[c] += sww[c * 18 + base];
        }
      }
#pragma unroll
      for (int s = 0; s < 4; ++s)
        tb[(kh * 4 + s) * 64 + v] =
            make_float4(e[4 * s], e[4 * s + 1], e[4 * s + 2], e[4 * s + 3]);
    }
    __syncthreads();

    int gid = bid * 256 + tid;              // (b, h1, w1)
    int h1 = (gid >> 6) & 63, b = gid >> 12;
    int lane = tid & 63;
    float bias_r[16], beta_r[16];
#pragma unroll
    for (int c = 0; c < 16; ++c) { bias_r[c] = bias[c]; beta_r[c] = beta[c]; }
    float mem[16], bth[16];
#pragma unroll
    for (int c = 0; c < 16; ++c) { mem[c] = 0.f; bth[c] = 0.f; }

    int y0 = 2 * h1 - 1;
    bool vtop = (y0 >= 0);                  // only h1==0 has an invalid top row
    const float* xb = x + (size_t)(b * T) * 2 * 16384 + 2 * lane;

    float2 cur[6];                          // [ci*3+kh]
#pragma unroll
    for (int ci = 0; ci < 2; ++ci)
#pragma unroll
      for (int kh = 0; kh < 3; ++kh) {
        int j = ci * 3 + kh;
        cur[j] = (kh == 0 && !vtop) ? make_float2(0.f, 0.f)
               : *(const float2*)(xb + ci * 16384 + (y0 + kh) * 128);
      }

    for (int t = 0; t < T; ++t) {
      int r = b * T + t;
      float2 nxt[6];
      if (t + 1 < T) {                      // prefetch next timestep's rows
        const float* xn = xb + (size_t)(t + 1) * 32768;
#pragma unroll
        for (int ci = 0; ci < 2; ++ci)
#pragma unroll
          for (int kh = 0; kh < 3; ++kh) {
            int j = ci * 3 + kh;
            nxt[j] = (kh == 0 && !vtop) ? make_float2(0.f, 0.f)
                   : *(const float2*)(xn + ci * 16384 + (y0 + kh) * 128);
          }
      }
      // build M: bit position 3*j + {0:left,1:mid,2:right}, j = ci*3+kh
      uint32_t Mc = 0, Rr = 0;
#pragma unroll
      for (int j = 0; j < 6; ++j) {
        float2 v = cur[j];
        uint32_t bm = (v.x != 0.f) ? 1u : 0u;
        uint32_t br = (v.y != 0.f) ? 1u : 0u;
        Mc |= ((bm << 1) | (br << 2)) << (3 * j);
        Rr |= br << j;
      }
      uint32_t RL = (uint32_t)__shfl((int)Rr, lane - 1, 64);  // one shuffle
      if (lane == 0) RL = 0u;
      uint32_t M = Mc | (RL & 1u) | ((RL & 2u) << 2) | ((RL & 4u) << 4)
                 | ((RL & 8u) << 6) | ((RL & 16u) << 8) | ((RL & 32u) << 10);
      int i0 = (int)((M & 7u)         | (((M >> 9) & 7u) << 3));
      int i1 = (int)(((M >> 3) & 7u)  | (((M >> 12) & 7u) << 3));
      int i2 = (int)(((M >> 6) & 7u)  | (((M >> 15) & 7u) << 3));
      float acc[16];
#pragma unroll
      for (int s = 0; s < 4; ++s) {
        float4 u0 = tb[s * 64 + i0];
        float4 u1 = tb[(4 + s) * 64 + i1];
        float4 u2 = tb[(8 + s) * 64 + i2];
        acc[4 * s + 0] = bias_r[4 * s + 0] + u0.x + u1.x + u2.x;
        acc[4 * s + 1] = bias_r[4 * s + 1] + u0.y + u1.y + u2.y;
        acc[4 * s + 2] = bias_r[4 * s + 2] + u0.z + u1.z + u2.z;
        acc[4 * s + 3] = bias_r[4 * s + 3] + u0.w + u1.w + u2.w;
      }
      uint32_t mask = 0;
#pragma unroll
      for (int c = 0; c < 16; ++c) {
        mem[c] = beta_r[c] * mem[c] + acc[c];
        float th = V_TH + bth[c];
        bool s = (mem[c] >= th);
        if (s) { mem[c] -= th; mask |= (1u << c); }
        bth[c] = RHO * bth[c] + (s ? ADAPT : 0.f);
      }
      int iL = 2 * lane - 1; if (iL < 0) iL = 0;
      uint32_t mL = __shfl((int)mask, iL, 64);
      uint32_t mC = __shfl((int)mask, 2 * lane, 64);
      uint32_t mR = __shfl((int)mask, 2 * lane + 1, 64);
      if (lane < 32) {
        uint64_t tw = (uint64_t)(lane ? mL : 0u) | ((uint64_t)mC << 16) |
                      ((uint64_t)mR << 32);
        trip[(size_t)(r * H1 + h1) * 32 + lane] = tw;
      }
      if (t + 1 < T) {
#pragma unroll
        for (int j = 0; j < 6; ++j) cur[j] = nxt[j];
      }
    }
  } else if (bid < 1536) {
    // transpose with channel permutation pos(c)=(c&3)*8+(c>>2):
    // pwt[(p*32+pos(c))*64+d] = pw[d*32768 + c*1024 + p]
    float* tile = shmem;
    int tb = bid - 1024;
    int c = tb >> 4, pt = tb & 15;
    int posc = ((c & 3) << 3) + (c >> 2);
    int p0 = pt * 64;
    int lane = tid & 63, quad = tid >> 6;
#pragma unroll
    for (int it = 0; it < 16; ++it) {
      int d = it * 4 + quad;
      tile[d * 65 + lane] = pw[(size_t)d * FLAT + c * 1024 + p0 + lane];
    }
    __syncthreads();
#pragma unroll
    for (int it = 0; it < 16; ++it) {
      int pp = it * 4 + quad;
      pwt[((size_t)((p0 + pp) * 32 + posc)) * 64 + lane] = tile[lane * 65 + pp];
    }
  } else if (bid == 1536) {
    if (tid == 0) *cnt = 0u;
  } else {
    // conv2 12-bit table, groups 0..7 (kh0,kh1) only:
    // tbl[((kh*4+gp)*4096+v)*32+co] = sum of group's cols
    int idx = bid - 1537;               // 0..127
    int g = idx >> 4;                   // 0..7 = kh*4+gp
    int kh = g >> 2, gp = g & 3;
    int v = ((idx & 15) << 8) + tid;    // 0..4095
    float e[32];
#pragma unroll
    for (int co = 0; co < 32; ++co) e[co] = 0.f;
    for (int i = 0; i < 12; ++i) {
      if ((v >> i) & 1) {
        int j = gp * 12 + i;            // trip bit = kw*16 + ci
        int kw = j >> 4, ci = j & 15;
#pragma unroll
        for (int co = 0; co < 32; ++co)
          e[co] += c2w[((co * 16 + ci) * 3 + kh) * 3 + kw];
      }
    }
#pragma unroll
    for (int co = 0; co < 32; ++co)
      tbl[((size_t)(g * 4096 + v)) * 32 + co] = e[co];
  }
}

// ---------------- stage 2: conv(16->32,s2,p1), HYBRID ----------------------
// 8 px/wave, 8 lanes/px (li = 4 co each).
// kh0,kh1 (groups 0..7): global 12-bit table gathers (L2 pipe, 8/t).
// kh2: spike-driven scan from 6.9 KB LDS weights (LDS pipe, ~14 reads/t).
// R8 measured 44.5us (vs 52.6 full-LDS); FETCH 6.4MB -> table L2-resident;
// remaining floor is the per-t dependency chain. trip t+1 prefetched.
__global__ __launch_bounds__(256) void k_conv2_lif2(
    const uint64_t* __restrict__ trip, const float* __restrict__ tbl,
    const float* __restrict__ c2w,
    const float* __restrict__ bias, const float* __restrict__ beta,
    uint32_t* __restrict__ bits, unsigned int* __restrict__ cnt) {
  __shared__ __align__(16) float wl[48 * 36];    // kh2 weights, 6.9 KB
  __shared__ unsigned int sc;
  int tid = threadIdx.x;
  if (tid == 0) sc = 0u;
  for (int i = tid; i < 1536; i += 256) {        // 6 iterations exactly
    int row = i >> 5, co = i & 31;               // row = kw*16 + ci (bit index)
    int kw = row >> 4, ci = row & 15;
    wl[row * 36 + co] = c2w[((co * 16 + ci) * 3 + 2) * 3 + kw];
  }
  __syncthreads();
  int lane = tid & 63;
  int li = lane & 7;
  int p8 = lane >> 3;
  int wvi = (blockIdx.x * 256 + tid) >> 6;
  int px = wvi * 8 + p8;
  int w2 = px & 31, h2 = (px >> 5) & 31, b = px >> 10;
  const float* wbase = wl + 4 * li;
  float4 b4 = *(const float4*)&bias[4 * li];
  float4 bt4 = *(const float4*)&beta[4 * li];
  float m0v = 0.f, m1v = 0.f, m2v = 0.f, m3v = 0.f;
  float t0 = 0.f, t1 = 0.f, t2 = 0.f, t3 = 0.f;
  unsigned int lc = 0;
  const float4* tb4 = (const float4*)tbl;   // [g][v][li] float4, g<8
  const uint64_t* trb = trip + ((size_t)(b * T) * 64 + 2 * h2) * 32 + w2;
  uint64_t q0 = (h2 > 0) ? trb[-32] : 0ull;
  uint64_t q1 = trb[0];
  uint64_t q2 = trb[32];
  for (int t = 0; t < T; ++t) {
    int r = b * T + t;
    uint64_t n0 = 0ull, n1 = 0ull, n2 = 0ull;
    if (t + 1 < T) {                        // prefetch next timestep's trip
      const uint64_t* trn = trb + (size_t)(t + 1) * 2048;
      n0 = (h2 > 0) ? trn[-32] : 0ull;
      n1 = trn[0];
      n2 = trn[32];
    }
    uint32_t r0l = (uint32_t)q0, r0h = (uint32_t)(q0 >> 32);
    uint32_t r1l = (uint32_t)q1, r1h = (uint32_t)(q1 >> 32);
    // issue the 8 independent table gathers (kh0,kh1) — L2 pipe
    float4 v0 = tb4[(0 << 15) + ((r0l & 4095u) << 3) + li];
    float4 v1 = tb4[(1 << 15) + (((r0l >> 12) & 4095u) << 3) + li];
    float4 v2 = tb4[(2 << 15) + ((((r0l >> 24) | (r0h << 8)) & 4095u) << 3) + li];
    float4 v3 = tb4[(3 << 15) + (((r0h >> 4) & 4095u) << 3) + li];
    float4 v4 = tb4[(4 << 15) + ((r1l & 4095u) << 3) + li];
    float4 v5 = tb4[(5 << 15) + (((r1l >> 12) & 4095u) << 3) + li];
    float4 v6 = tb4[(6 << 15) + ((((r1l >> 24) | (r1h << 8)) & 4095u) << 3) + li];
    float4 v7 = tb4[(7 << 15) + (((r1h >> 4) & 4095u) << 3) + li];
    // kh2 spike-scan from LDS — runs while gathers are in flight
    float C0 = 0.f, C1 = 0.f, C2 = 0.f, C3 = 0.f;
#pragma unroll
    for (int gp = 0; gp < 4; ++gp) {
      uint32_t m = (uint32_t)(q2 >> (12 * gp)) & 0xFFFu;
      float g0 = 0.f, g1 = 0.f, g2 = 0.f, g3 = 0.f;
      while (m) {
        int i = __ffs(m) - 1; m &= m - 1;
        float4 wv = *(const float4*)(wbase + (gp * 12 + i) * 36);
        g0 += wv.x; g1 += wv.y; g2 += wv.z; g3 += wv.w;
      }
      C0 += g0; C1 += g1; C2 += g2; C3 += g3;
    }
    // kh0 chain (includes bias, preserving the established prefix order)
    float A0 = b4.x + v0.x + v1.x + v2.x + v3.x;
    float A1 = b4.y + v0.y + v1.y + v2.y + v3.y;
    float A2 = b4.z + v0.z + v1.z + v2.z + v3.z;
    float A3 = b4.w + v0.w + v1.w + v2.w + v3.w;
    // kh1 chain
    float B0 = v4.x + v5.x + v6.x + v7.x;
    float B1 = v4.y + v5.y + v6.y + v7.y;
    float B2 = v4.z + v5.z + v6.z + v7.z;
    float B3 = v4.w + v5.w + v6.w + v7.w;
    float a0 = (A0 + B0) + C0, a1 = (A1 + B1) + C1;
    float a2 = (A2 + B2) + C2, a3 = (A3 + B3) + C3;
    m0v = bt4.x * m0v + a0;
    m1v = bt4.y * m1v + a1;
    m2v = bt4.z * m2v + a2;
    m3v = bt4.w * m3v + a3;
    float th0 = V_TH + t0, th1 = V_TH + t1, th2 = V_TH + t2, th3 = V_TH + t3;
    bool s0 = (m0v >= th0), s1 = (m1v >= th1), s2 = (m2v >= th2), s3 = (m3v >= th3);
    if (s0) m0v -= th0;
    if (s1) m1v -= th1;
    if (s2) m2v -= th2;
    if (s3) m3v -= th3;
    t0 = RHO * t0 + (s0 ? ADAPT : 0.f);
    t1 = RHO * t1 + (s1 ? ADAPT : 0.f);
    t2 = RHO * t2 + (s2 ? ADAPT : 0.f);
    t3 = RHO * t3 + (s3 ? ADAPT : 0.f);
    unsigned long long bl0 = __ballot(s0);
    unsigned long long bl1 = __ballot(s1);
    unsigned long long bl2 = __ballot(s2);
    unsigned long long bl3 = __ballot(s3);
    if (li == 0) {
      int sh = p8 * 8;
      uint32_t m32 = ((uint32_t)(bl0 >> sh) & 0xFFu)
                   | (((uint32_t)(bl1 >> sh) & 0xFFu) << 8)
                   | (((uint32_t)(bl2 >> sh) & 0xFFu) << 16)
                   | (((uint32_t)(bl3 >> sh) & 0xFFu) << 24);
      bits[(size_t)r * 1024 + (px & 1023)] = m32;
      lc += __popc(m32);
    }
    q0 = n0; q1 = n1; q2 = n2;
  }
  if (li == 0) atomicAdd(&sc, lc);
  __syncthreads();
  if (tid == 0) atomicAdd(cnt, sc);
}

// ---------------- sparse proj GEMM: OR-dedup row scan -----------------------
// 1024 blocks x 256: block = (rt, 4 ks), wave = one ks split (16 words).
// R9's 8-way interleave removed latency but hit the gather-BANDWIDTH floor:
// each set bit = one 256B pwt row read, and the 8 timestep-rows re-read the
// same row when a channel spikes at multiple t (mean redundancy ~1.6-1.9x).
// NEW: scan the OR of the 8 masks; load each spiking channel's row ONCE and
// add it into exactly the accumulators whose mask has that bit (wave-uniform
// guards). BIT-EXACT: per accumulator, adds keep word order + ascending-bit
// order (iterating OR ascending visits each mask's bits ascending).
// Next word's masks prefetched. Block's 4 ks-waves reduced via LDS.
__global__ __launch_bounds__(256) void k_proj_gemm(
    const uint32_t* __restrict__ bits, const float* __restrict__ pwt,
    float* __restrict__ partial) {
  __shared__ float red[4][8][64];
  int rt = blockIdx.x >> 4;
  int blk = blockIdx.x & 15;
  int wv = threadIdx.x >> 6;
  int ks = blk * 4 + wv;
  int d = threadIdx.x & 63;
  float a0 = 0.f, a1 = 0.f, a2 = 0.f, a3 = 0.f;
  float a4 = 0.f, a5 = 0.f, a6 = 0.f, a7 = 0.f;
  const uint32_t* bb = bits + (size_t)rt * 8 * 1024;
  int word0 = ks * 16;
  uint32_t m0 = bb[word0],          m1 = bb[1024 + word0];
  uint32_t m2 = bb[2048 + word0],   m3 = bb[3072 + word0];
  uint32_t m4 = bb[4096 + word0],   m5 = bb[5120 + word0];
  uint32_t m6 = bb[6144 + word0],   m7 = bb[7168 + word0];
  for (int wi = 0; wi < 16; ++wi) {
    int word = word0 + wi;
    const float* rowbase = pwt + ((size_t)word * 32) * 64 + d;
    uint32_t n0 = 0u, n1 = 0u, n2 = 0u, n3 = 0u;
    uint32_t n4 = 0u, n5 = 0u, n6 = 0u, n7 = 0u;
    if (wi + 1 < 16) {                       // prefetch next word's masks
      int wn = word + 1;
      n0 = bb[wn];          n1 = bb[1024 + wn];
      n2 = bb[2048 + wn];   n3 = bb[3072 + wn];
      n4 = bb[4096 + wn];   n5 = bb[5120 + wn];
      n6 = bb[6144 + wn];   n7 = bb[7168 + wn];
    }
    uint32_t u = m0 | m1 | m2 | m3 | m4 | m5 | m6 | m7;
    while (u) {
      int c = __ffs(u) - 1;
      uint32_t bit = u & (~u + 1u);          // lowest set bit
      u &= u - 1;
      float wrow = rowbase[c << 6];          // one 256B row load per channel
      if (m0 & bit) a0 += wrow;
      if (m1 & bit) a1 += wrow;
      if (m2 & bit) a2 += wrow;
      if (m3 & bit) a3 += wrow;
      if (m4 & bit) a4 += wrow;
      if (m5 & bit) a5 += wrow;
      if (m6 & bit) a6 += wrow;
      if (m7 & bit) a7 += wrow;
    }
    m0 = n0; m1 = n1; m2 = n2; m3 = n3;
    m4 = n4; m5 = n5; m6 = n6; m7 = n7;
  }
  red[wv][0][d] = a0; red[wv][1][d] = a1;
  red[wv][2][d] = a2; red[wv][3][d] = a3;
  red[wv][4][d] = a4; red[wv][5][d] = a5;
  red[wv][6][d] = a6; red[wv][7][d] = a7;
  __syncthreads();
  if (wv == 0) {
#pragma unroll
    for (int ri = 0; ri < 8; ++ri) {
      float s = ((red[0][ri][d] + red[1][ri][d]) + red[2][ri][d]) + red[3][ri][d];
      partial[((size_t)(rt * 16 + blk) * 8 + ri) * 64 + d] = s;
    }
  }
}

// ------- reduce + MHA + mean + output LIF + classifier + sparsity ----------
__global__ __launch_bounds__(256) void k_attn_final(
    const float* __restrict__ partial, const float* __restrict__ pb,
    const float* __restrict__ wq, const float* __restrict__ wk,
    const float* __restrict__ wv, const float* __restrict__ wo,
    const float* __restrict__ clsw, const float* __restrict__ clsb,
    const unsigned int* __restrict__ cnt, float* __restrict__ out) {
  __shared__ float swq[64 * 65], swk[64 * 65], swv[64 * 65], swo[64 * 65];
  __shared__ float sp[8 * 65], sq[8 * 65], sk[8 * 65], sv[8 * 65], so2[8 * 65];
  __shared__ float satt[4][8][8];
  __shared__ float sob[64];
  int b = blockIdx.x, tid = threadIdx.x;
  for (int i = tid; i < 4096; i += 256) {
    int dd = i >> 6, e = i & 63;
    swq[dd * 65 + e] = wq[i]; swk[dd * 65 + e] = wk[i];
    swv[dd * 65 + e] = wv[i]; swo[dd * 65 + e] = wo[i];
  }
  // fused proj reduction: sp[ri][d] = pb[d] + sum_k16 partial[b][k16][ri][d]
  for (int i = tid; i < 512; i += 256) {
    int ri = i >> 6, d = i & 63;
    float s = pb[d];
    const float* p = partial + ((size_t)(b * 16) * 8 + ri) * 64 + d;
#pragma unroll
    for (int k16 = 0; k16 < 16; ++k16) s += p[(size_t)k16 * 512];
    sp[ri * 65 + d] = s;
  }
  __syncthreads();
#pragma unroll
  for (int p = 0; p < 2; ++p) {
    int idx = p * 256 + tid, t = idx >> 6, d = idx & 63;
    float qa = 0.f, ka = 0.f, va = 0.f;
    for (int e = 0; e < 64; ++e) {
      float pe = sp[t * 65 + e];
      qa += pe * swq[d * 65 + e];
      ka += pe * swk[d * 65 + e];
      va += pe * swv[d * 65 + e];
    }
    sq[t * 65 + d] = qa; sk[t * 65 + d] = ka; sv[t * 65 + d] = va;
  }
  __syncthreads();
  {
    int h = tid >> 6, q = (tid >> 3) & 7, k = tid & 7;
    float s = 0.f;
    for (int j = 0; j < 16; ++j)
      s += sq[q * 65 + h * 16 + j] * sk[k * 65 + h * 16 + j];
    satt[h][q][k] = s * 0.25f;
  }
  __syncthreads();
  if (tid < 32) {
    int h = tid >> 3, q2 = tid & 7;
    float m = -1e30f;
    for (int k2 = 0; k2 < 8; ++k2) m = fmaxf(m, satt[h][q2][k2]);
    float sum = 0.f;
    for (int k2 = 0; k2 < 8; ++k2) {
      float e = expf(satt[h][q2][k2] - m);
      satt[h][q2][k2] = e; sum += e;
    }
    float inv = 1.f / sum;
    for (int k2 = 0; k2 < 8; ++k2) satt[h][q2][k2] *= inv;
  }
  __syncthreads();
#pragma unroll
  for (int p = 0; p < 2; ++p) {
    int idx = p * 256 + tid, t = idx >> 6, d = idx & 63;
    int h = d >> 4;
    float o = 0.f;
    for (int k = 0; k < 8; ++k) o += satt[h][t][k] * sv[k * 65 + d];
    so2[t * 65 + d] = o;
  }
  __syncthreads();
  if (tid < 64) {
    float ob = 0.f;
    for (int t = 0; t < 8; ++t) ob += so2[t * 65 + tid];
    sob[tid] = ob * 0.125f;
  }
  __syncthreads();
  if (tid < 64) {
    float ctx = 0.f;
    for (int e = 0; e < 64; ++e) ctx += sob[e] * swo[tid * 65 + e];
    int spk = (ctx >= V_TH) ? 1 : 0;
    unsigned long long ball = __ballot(spk);
    if (tid < 2) {
      float lg = clsb[tid];
      for (int dd = 0; dd < 64; ++dd)
        if ((ball >> dd) & 1ull) lg += clsw[tid * 64 + dd];
      out[b * 2 + tid] = lg;
    }
    if (b == 0 && tid == 2)
      out[128] = 1.f - (float)(*cnt) / 16777216.f;
  }
}

extern "C" void kernel_launch(void* const* d_in, const int* in_sizes, int n_in,
                              void* d_out, int out_size, void* d_ws, size_t ws_size,
                              hipStream_t stream) {
  const float* x    = (const float*)d_in[0];
  const float* c1w  = (const float*)d_in[1];
  const float* c1b  = (const float*)d_in[2];
  const float* c2w  = (const float*)d_in[3];
  const float* c2b  = (const float*)d_in[4];
  const float* bt1  = (const float*)d_in[5];
  const float* bt2  = (const float*)d_in[6];
  const float* pw   = (const float*)d_in[7];
  const float* pb   = (const float*)d_in[8];
  const float* wq   = (const float*)d_in[9];
  const float* wk   = (const float*)d_in[10];
  const float* wv   = (const float*)d_in[11];
  const float* wo   = (const float*)d_in[12];
  const float* clsw = (const float*)d_in[13];
  const float* clsb = (const float*)d_in[14];
  float* out = (float*)d_out;

  uint8_t* ws = (uint8_t*)d_ws;
  uint64_t* trip  = (uint64_t*)(ws + OFF_TRIP);
  uint32_t* bits  = (uint32_t*)(ws + OFF_BITS);
  float*    pwt   = (float*)(ws + OFF_PWT);
  unsigned int* cnt = (unsigned int*)(ws + OFF_CNT);
  float*    tbl   = (float*)(ws + OFF_TBL);
  float*    part  = (float*)(ws + OFF_PART);

  k_mega1<<<1665, 256, 0, stream>>>(x, c1w, c1b, bt1, trip, pw, pwt, c2w, tbl, cnt);
  k_conv2_lif2<<<2048, 256, 0, stream>>>(trip, tbl, c2w, c2b, bt2, bits, cnt);
  k_proj_gemm<<<1024, 256, 0, stream>>>(bits, pwt, part);
  k_attn_final<<<64, 256, 0, stream>>>(part, pb, wq, wk, wv, wo, clsw, clsb, cnt, out);
}

// Round 11
// 194.157 us; speedup vs baseline: 1.0804x; 1.0161x over previous
//
#include <hip/hip_runtime.h>
#include <cstdint>

#define V_TH 1.0f
#define RHO 0.9f
#define ADAPT 0.1f

static constexpr int B = 64, T = 8, C = 2, H = 128, W = 128;
static constexpr int H1 = 64, W1 = 64;
static constexpr int H2 = 32, W2 = 32;
static constexpr int FLAT = 32 * H2 * W2;   // 32768
static constexpr int R = B * T;             // 512

// workspace layout (bytes) — full 12-group tbl (6 MB) restored (R5 config)
static constexpr size_t OFF_TRIP  = 0;                          // u64 [512*64*32] = 8 MB
static constexpr size_t OFF_BITS  = OFF_TRIP + 8388608;         // u32 [512*1024]  = 2 MB
static constexpr size_t OFF_PWT   = OFF_BITS + 2097152;         // f32 [32768*64]  = 8 MB
static constexpr size_t OFF_CNT   = OFF_PWT + 8388608;
static constexpr size_t OFF_TBL   = OFF_CNT + 256;              // f32 [12*4096*32] = 6 MB
static constexpr size_t OFF_PART  = OFF_TBL + 6291456;          // f32 [64*16*8*64] = 2 MB

// ---------------- mega1: conv1+LIF1 | transpose | cnt | table12 -------------
// blocks: [0,1024) conv1, [1024,1536) transpose, 1536 cnt, [1537,1729) table
// conv1: R1-proven configuration (measured ~41-43 us, 60 VGPR, 8 waves/SIMD).
// R2 (channel-split), R3 (array depth-2 -> scratch), R4 (named-reg depth-2 ->
// VGPR cliff) all measured SLOWER — do not touch without new counter evidence.
// Table: FULL 12 groups restored. R10 post-mortem: the hybrid conv2 (8-group
// table + kh2 LDS scan) measured 43.5-44.8us vs <=40.6 for the full-table
// conv2 in the R5 build — the divergent kh2 scan's VALU cost exceeds the
// 4 gathers it saves. This round recombines best-measured components.
__global__ __launch_bounds__(256) void k_mega1(
    const float* __restrict__ x, const float* __restrict__ w,
    const float* __restrict__ bias, const float* __restrict__ beta,
    uint64_t* __restrict__ trip,
    const float* __restrict__ pw, float* __restrict__ pwt,
    const float* __restrict__ c2w, float* __restrict__ tbl,
    unsigned int* __restrict__ cnt) {
  __shared__ __align__(16) float shmem[64 * 65];  // conv1: tables+weights; transpose: tile
  int bid = blockIdx.x;
  int tid = threadIdx.x;
  if (bid < 1024) {
    float4* tb = (float4*)shmem;            // [kh*4+s][64] float4 entries (3072 floats)
    float* sww = shmem + 3072;              // staged weights [288]
    for (int i = tid; i < 288; i += 256) sww[i] = w[i];
    __syncthreads();
    if (tid < 192) {                        // build tables: entry (kh, v)
      int kh = tid >> 6, v = tid & 63;
      float e[16];
#pragma unroll
      for (int c = 0; c < 16; ++c) e[c] = 0.f;
#pragma unroll
      for (int bbit = 0; bbit < 6; ++bbit) {
        if ((v >> bbit) & 1) {
          int ci = (bbit >= 3) ? 1 : 0;
          int kw = bbit - ci * 3;
          int base = ci * 9 + kh * 3 + kw;  // w[c][ci][kh][kw] = w[c*18 + base]
#pragma unroll
          for (int c = 0; c < 16; ++c) e[c] += sww[c * 18 + base];
        }
      }
#pragma unroll
      for (int s = 0; s < 4; ++s)
        tb[(kh * 4 + s) * 64 + v] =
            make_float4(e[4 * s], e[4 * s + 1], e[4 * s + 2], e[4 * s + 3]);
    }
    __syncthreads();

    int gid = bid * 256 + tid;              // (b, h1, w1)
    int h1 = (gid >> 6) & 63, b = gid >> 12;
    int lane = tid & 63;
    float bias_r[16], beta_r[16];
#pragma unroll
    for (int c = 0; c < 16; ++c) { bias_r[c] = bias[c]; beta_r[c] = beta[c]; }
    float mem[16], bth[16];
#pragma unroll
    for (int c = 0; c < 16; ++c) { mem[c] = 0.f; bth[c] = 0.f; }

    int y0 = 2 * h1 - 1;
    bool vtop = (y0 >= 0);                  // only h1==0 has an invalid top row
    const float* xb = x + (size_t)(b * T) * 2 * 16384 + 2 * lane;

    float2 cur[6];                          // [ci*3+kh]
#pragma unroll
    for (int ci = 0; ci < 2; ++ci)
#pragma unroll
      for (int kh = 0; kh < 3; ++kh) {
        int j = ci * 3 + kh;
        cur[j] = (kh == 0 && !vtop) ? make_float2(0.f, 0.f)
               : *(const float2*)(xb + ci * 16384 + (y0 + kh) * 128);
      }

    for (int t = 0; t < T; ++t) {
      int r = b * T + t;
      float2 nxt[6];
      if (t + 1 < T) {                      // prefetch next timestep's rows
        const float* xn = xb + (size_t)(t + 1) * 32768;
#pragma unroll
        for (int ci = 0; ci < 2; ++ci)
#pragma unroll
          for (int kh = 0; kh < 3; ++kh) {
            int j = ci * 3 + kh;
            nxt[j] = (kh == 0 && !vtop) ? make_float2(0.f, 0.f)
                   : *(const float2*)(xn + ci * 16384 + (y0 + kh) * 128);
          }
      }
      // build M: bit position 3*j + {0:left,1:mid,2:right}, j = ci*3+kh
      uint32_t Mc = 0, Rr = 0;
#pragma unroll
      for (int j = 0; j < 6; ++j) {
        float2 v = cur[j];
        uint32_t bm = (v.x != 0.f) ? 1u : 0u;
        uint32_t br = (v.y != 0.f) ? 1u : 0u;
        Mc |= ((bm << 1) | (br << 2)) << (3 * j);
        Rr |= br << j;
      }
      uint32_t RL = (uint32_t)__shfl((int)Rr, lane - 1, 64);  // one shuffle
      if (lane == 0) RL = 0u;
      uint32_t M = Mc | (RL & 1u) | ((RL & 2u) << 2) | ((RL & 4u) << 4)
                 | ((RL & 8u) << 6) | ((RL & 16u) << 8) | ((RL & 32u) << 10);
      int i0 = (int)((M & 7u)         | (((M >> 9) & 7u) << 3));
      int i1 = (int)(((M >> 3) & 7u)  | (((M >> 12) & 7u) << 3));
      int i2 = (int)(((M >> 6) & 7u)  | (((M >> 15) & 7u) << 3));
      float acc[16];
#pragma unroll
      for (int s = 0; s < 4; ++s) {
        float4 u0 = tb[s * 64 + i0];
        float4 u1 = tb[(4 + s) * 64 + i1];
        float4 u2 = tb[(8 + s) * 64 + i2];
        acc[4 * s + 0] = bias_r[4 * s + 0] + u0.x + u1.x + u2.x;
        acc[4 * s + 1] = bias_r[4 * s + 1] + u0.y + u1.y + u2.y;
        acc[4 * s + 2] = bias_r[4 * s + 2] + u0.z + u1.z + u2.z;
        acc[4 * s + 3] = bias_r[4 * s + 3] + u0.w + u1.w + u2.w;
      }
      uint32_t mask = 0;
#pragma unroll
      for (int c = 0; c < 16; ++c) {
        mem[c] = beta_r[c] * mem[c] + acc[c];
        float th = V_TH + bth[c];
        bool s = (mem[c] >= th);
        if (s) { mem[c] -= th; mask |= (1u << c); }
        bth[c] = RHO * bth[c] + (s ? ADAPT : 0.f);
      }
      int iL = 2 * lane - 1; if (iL < 0) iL = 0;
      uint32_t mL = __shfl((int)mask, iL, 64);
      uint32_t mC = __shfl((int)mask, 2 * lane, 64);
      uint32_t mR = __shfl((int)mask, 2 * lane + 1, 64);
      if (lane < 32) {
        uint64_t tw = (uint64_t)(lane ? mL : 0u) | ((uint64_t)mC << 16) |
                      ((uint64_t)mR << 32);
        trip[(size_t)(r * H1 + h1) * 32 + lane] = tw;
      }
      if (t + 1 < T) {
#pragma unroll
        for (int j = 0; j < 6; ++j) cur[j] = nxt[j];
      }
    }
  } else if (bid < 1536) {
    // transpose with channel permutation pos(c)=(c&3)*8+(c>>2):
    // pwt[(p*32+pos(c))*64+d] = pw[d*32768 + c*1024 + p]
    float* tile = shmem;
    int tb = bid - 1024;
    int c = tb >> 4, pt = tb & 15;
    int posc = ((c & 3) << 3) + (c >> 2);
    int p0 = pt * 64;
    int lane = tid & 63, quad = tid >> 6;
#pragma unroll
    for (int it = 0; it < 16; ++it) {
      int d = it * 4 + quad;
      tile[d * 65 + lane] = pw[(size_t)d * FLAT + c * 1024 + p0 + lane];
    }
    __syncthreads();
#pragma unroll
    for (int it = 0; it < 16; ++it) {
      int pp = it * 4 + quad;
      pwt[((size_t)((p0 + pp) * 32 + posc)) * 64 + lane] = tile[lane * 65 + pp];
    }
  } else if (bid == 1536) {
    if (tid == 0) *cnt = 0u;
  } else {
    // conv2 12-bit table: tbl[((kh*4+gp)*4096+v)*32+co] = sum of group's cols
    int idx = bid - 1537;               // 0..191
    int g = idx >> 4;                   // 0..11 = kh*4+gp
    int kh = g >> 2, gp = g & 3;
    int v = ((idx & 15) << 8) + tid;    // 0..4095
    float e[32];
#pragma unroll
    for (int co = 0; co < 32; ++co) e[co] = 0.f;
    for (int i = 0; i < 12; ++i) {
      if ((v >> i) & 1) {
        int j = gp * 12 + i;            // trip bit = kw*16 + ci
        int kw = j >> 4, ci = j & 15;
#pragma unroll
        for (int co = 0; co < 32; ++co)
          e[co] += c2w[((co * 16 + ci) * 3 + kh) * 3 + kw];
      }
    }
#pragma unroll
    for (int co = 0; co < 32; ++co)
      tbl[((size_t)(g * 4096 + v)) * 32 + co] = e[co];
  }
}

// ---------------- stage 2: conv(16->32,s2,p1) via 12-bit tables, 8 px/wave --
// R5-proven full-table version (measured <=40.6us in the R5 build): 12
// independent gathers per t, 3 per-kh fold chains, trip t+1 prefetched.
// R7 (full-LDS scan, 52.6) and R8-R10 (hybrid, 43.5-44.8) both measured
// SLOWER — the divergent spike-scan's VALU cost exceeds the gathers saved.
__global__ __launch_bounds__(256) void k_conv2_lif2(
    const uint64_t* __restrict__ trip, const float* __restrict__ tbl,
    const float* __restrict__ bias, const float* __restrict__ beta,
    uint32_t* __restrict__ bits, unsigned int* __restrict__ cnt) {
  __shared__ unsigned int sc;
  int tid = threadIdx.x;
  if (tid == 0) sc = 0u;
  __syncthreads();
  int lane = tid & 63;
  int li = lane & 7;
  int p8 = lane >> 3;
  int wvi = (blockIdx.x * 256 + tid) >> 6;
  int px = wvi * 8 + p8;
  int w2 = px & 31, h2 = (px >> 5) & 31, b = px >> 10;
  float4 b4 = *(const float4*)&bias[4 * li];
  float4 bt4 = *(const float4*)&beta[4 * li];
  float m0v = 0.f, m1v = 0.f, m2v = 0.f, m3v = 0.f;
  float t0 = 0.f, t1 = 0.f, t2 = 0.f, t3 = 0.f;
  unsigned int lc = 0;
  const float4* tb4 = (const float4*)tbl;   // [g][v][li] float4
  const uint64_t* trb = trip + ((size_t)(b * T) * 64 + 2 * h2) * 32 + w2;
  uint64_t q0 = (h2 > 0) ? trb[-32] : 0ull;
  uint64_t q1 = trb[0];
  uint64_t q2 = trb[32];
  for (int t = 0; t < T; ++t) {
    int r = b * T + t;
    uint64_t n0 = 0ull, n1 = 0ull, n2 = 0ull;
    if (t + 1 < T) {                        // prefetch next timestep's trip
      const uint64_t* trn = trb + (size_t)(t + 1) * 2048;
      n0 = (h2 > 0) ? trn[-32] : 0ull;
      n1 = trn[0];
      n2 = trn[32];
    }
    uint32_t r0l = (uint32_t)q0, r0h = (uint32_t)(q0 >> 32);
    uint32_t r1l = (uint32_t)q1, r1h = (uint32_t)(q1 >> 32);
    uint32_t r2l = (uint32_t)q2, r2h = (uint32_t)(q2 >> 32);
    // issue all 12 independent loads, then fold per-kh chains
    float4 v0 = tb4[(0 << 15) + ((r0l & 4095u) << 3) + li];
    float4 v1 = tb4[(1 << 15) + (((r0l >> 12) & 4095u) << 3) + li];
    float4 v2 = tb4[(2 << 15) + ((((r0l >> 24) | (r0h << 8)) & 4095u) << 3) + li];
    float4 v3 = tb4[(3 << 15) + (((r0h >> 4) & 4095u) << 3) + li];
    float4 v4 = tb4[(4 << 15) + ((r1l & 4095u) << 3) + li];
    float4 v5 = tb4[(5 << 15) + (((r1l >> 12) & 4095u) << 3) + li];
    float4 v6 = tb4[(6 << 15) + ((((r1l >> 24) | (r1h << 8)) & 4095u) << 3) + li];
    float4 v7 = tb4[(7 << 15) + (((r1h >> 4) & 4095u) << 3) + li];
    float4 v8 = tb4[(8 << 15) + ((r2l & 4095u) << 3) + li];
    float4 v9 = tb4[(9 << 15) + (((r2l >> 12) & 4095u) << 3) + li];
    float4 va = tb4[(10 << 15) + ((((r2l >> 24) | (r2h << 8)) & 4095u) << 3) + li];
    float4 vb = tb4[(11 << 15) + (((r2h >> 4) & 4095u) << 3) + li];
    // kh0 chain (includes bias, preserving the old prefix order)
    float A0 = b4.x + v0.x + v1.x + v2.x + v3.x;
    float A1 = b4.y + v0.y + v1.y + v2.y + v3.y;
    float A2 = b4.z + v0.z + v1.z + v2.z + v3.z;
    float A3 = b4.w + v0.w + v1.w + v2.w + v3.w;
    // kh1 chain
    float B0 = v4.x + v5.x + v6.x + v7.x;
    float B1 = v4.y + v5.y + v6.y + v7.y;
    float B2 = v4.z + v5.z + v6.z + v7.z;
    float B3 = v4.w + v5.w + v6.w + v7.w;
    // kh2 chain
    float C0 = v8.x + v9.x + va.x + vb.x;
    float C1 = v8.y + v9.y + va.y + vb.y;
    float C2 = v8.z + v9.z + va.z + vb.z;
    float C3 = v8.w + v9.w + va.w + vb.w;
    float a0 = (A0 + B0) + C0, a1 = (A1 + B1) + C1;
    float a2 = (A2 + B2) + C2, a3 = (A3 + B3) + C3;
    m0v = bt4.x * m0v + a0;
    m1v = bt4.y * m1v + a1;
    m2v = bt4.z * m2v + a2;
    m3v = bt4.w * m3v + a3;
    float th0 = V_TH + t0, th1 = V_TH + t1, th2 = V_TH + t2, th3 = V_TH + t3;
    bool s0 = (m0v >= th0), s1 = (m1v >= th1), s2 = (m2v >= th2), s3 = (m3v >= th3);
    if (s0) m0v -= th0;
    if (s1) m1v -= th1;
    if (s2) m2v -= th2;
    if (s3) m3v -= th3;
    t0 = RHO * t0 + (s0 ? ADAPT : 0.f);
    t1 = RHO * t1 + (s1 ? ADAPT : 0.f);
    t2 = RHO * t2 + (s2 ? ADAPT : 0.f);
    t3 = RHO * t3 + (s3 ? ADAPT : 0.f);
    unsigned long long bl0 = __ballot(s0);
    unsigned long long bl1 = __ballot(s1);
    unsigned long long bl2 = __ballot(s2);
    unsigned long long bl3 = __ballot(s3);
    if (li == 0) {
      int sh = p8 * 8;
      uint32_t m32 = ((uint32_t)(bl0 >> sh) & 0xFFu)
                   | (((uint32_t)(bl1 >> sh) & 0xFFu) << 8)
                   | (((uint32_t)(bl2 >> sh) & 0xFFu) << 16)
                   | (((uint32_t)(bl3 >> sh) & 0xFFu) << 24);
      bits[(size_t)r * 1024 + (px & 1023)] = m32;
      lc += __popc(m32);
    }
    q0 = n0; q1 = n1; q2 = n2;
  }
  if (li == 0) atomicAdd(&sc, lc);
  __syncthreads();
  if (tid == 0) atomicAdd(cnt, sc);
}

// ---------------- sparse proj GEMM: OR-dedup row scan -----------------------
// 1024 blocks x 256: block = (rt, 4 ks), wave = one ks split (16 words).
// R9+R10 proven: scan the OR of the 8 timestep masks; load each spiking
// channel's 256B pwt row ONCE, add into the accumulators whose mask has the
// bit (wave-uniform guards). BIT-EXACT per accumulator. Masks prefetched.
__global__ __launch_bounds__(256) void k_proj_gemm(
    const uint32_t* __restrict__ bits, const float* __restrict__ pwt,
    float* __restrict__ partial) {
  __shared__ float red[4][8][64];
  int rt = blockIdx.x >> 4;
  int blk = blockIdx.x & 15;
  int wv = threadIdx.x >> 6;
  int ks = blk * 4 + wv;
  int d = threadIdx.x & 63;
  float a0 = 0.f, a1 = 0.f, a2 = 0.f, a3 = 0.f;
  float a4 = 0.f, a5 = 0.f, a6 = 0.f, a7 = 0.f;
  const uint32_t* bb = bits + (size_t)rt * 8 * 1024;
  int word0 = ks * 16;
  uint32_t m0 = bb[word0],          m1 = bb[1024 + word0];
  uint32_t m2 = bb[2048 + word0],   m3 = bb[3072 + word0];
  uint32_t m4 = bb[4096 + word0],   m5 = bb[5120 + word0];
  uint32_t m6 = bb[6144 + word0],   m7 = bb[7168 + word0];
  for (int wi = 0; wi < 16; ++wi) {
    int word = word0 + wi;
    const float* rowbase = pwt + ((size_t)word * 32) * 64 + d;
    uint32_t n0 = 0u, n1 = 0u, n2 = 0u, n3 = 0u;
    uint32_t n4 = 0u, n5 = 0u, n6 = 0u, n7 = 0u;
    if (wi + 1 < 16) {                       // prefetch next word's masks
      int wn = word + 1;
      n0 = bb[wn];          n1 = bb[1024 + wn];
      n2 = bb[2048 + wn];   n3 = bb[3072 + wn];
      n4 = bb[4096 + wn];   n5 = bb[5120 + wn];
      n6 = bb[6144 + wn];   n7 = bb[7168 + wn];
    }
    uint32_t u = m0 | m1 | m2 | m3 | m4 | m5 | m6 | m7;
    while (u) {
      int c = __ffs(u) - 1;
      uint32_t bit = u & (~u + 1u);          // lowest set bit
      u &= u - 1;
      float wrow = rowbase[c << 6];          // one 256B row load per channel
      if (m0 & bit) a0 += wrow;
      if (m1 & bit) a1 += wrow;
      if (m2 & bit) a2 += wrow;
      if (m3 & bit) a3 += wrow;
      if (m4 & bit) a4 += wrow;
      if (m5 & bit) a5 += wrow;
      if (m6 & bit) a6 += wrow;
      if (m7 & bit) a7 += wrow;
    }
    m0 = n0; m1 = n1; m2 = n2; m3 = n3;
    m4 = n4; m5 = n5; m6 = n6; m7 = n7;
  }
  red[wv][0][d] = a0; red[wv][1][d] = a1;
  red[wv][2][d] = a2; red[wv][3][d] = a3;
  red[wv][4][d] = a4; red[wv][5][d] = a5;
  red[wv][6][d] = a6; red[wv][7][d] = a7;
  __syncthreads();
  if (wv == 0) {
#pragma unroll
    for (int ri = 0; ri < 8; ++ri) {
      float s = ((red[0][ri][d] + red[1][ri][d]) + red[2][ri][d]) + red[3][ri][d];
      partial[((size_t)(rt * 16 + blk) * 8 + ri) * 64 + d] = s;
    }
  }
}

// ------- reduce + MHA + mean + output LIF + classifier + sparsity ----------
__global__ __launch_bounds__(256) void k_attn_final(
    const float* __restrict__ partial, const float* __restrict__ pb,
    const float* __restrict__ wq, const float* __restrict__ wk,
    const float* __restrict__ wv, const float* __restrict__ wo,
    const float* __restrict__ clsw, const float* __restrict__ clsb,
    const unsigned int* __restrict__ cnt, float* __restrict__ out) {
  __shared__ float swq[64 * 65], swk[64 * 65], swv[64 * 65], swo[64 * 65];
  __shared__ float sp[8 * 65], sq[8 * 65], sk[8 * 65], sv[8 * 65], so2[8 * 65];
  __shared__ float satt[4][8][8];
  __shared__ float sob[64];
  int b = blockIdx.x, tid = threadIdx.x;
  for (int i = tid; i < 4096; i += 256) {
    int dd = i >> 6, e = i & 63;
    swq[dd * 65 + e] = wq[i]; swk[dd * 65 + e] = wk[i];
    swv[dd * 65 + e] = wv[i]; swo[dd * 65 + e] = wo[i];
  }
  // fused proj reduction: sp[ri][d] = pb[d] + sum_k16 partial[b][k16][ri][d]
  for (int i = tid; i < 512; i += 256) {
    int ri = i >> 6, d = i & 63;
    float s = pb[d];
    const float* p = partial + ((size_t)(b * 16) * 8 + ri) * 64 + d;
#pragma unroll
    for (int k16 = 0; k16 < 16; ++k16) s += p[(size_t)k16 * 512];
    sp[ri * 65 + d] = s;
  }
  __syncthreads();
#pragma unroll
  for (int p = 0; p < 2; ++p) {
    int idx = p * 256 + tid, t = idx >> 6, d = idx & 63;
    float qa = 0.f, ka = 0.f, va = 0.f;
    for (int e = 0; e < 64; ++e) {
      float pe = sp[t * 65 + e];
      qa += pe * swq[d * 65 + e];
      ka += pe * swk[d * 65 + e];
      va += pe * swv[d * 65 + e];
    }
    sq[t * 65 + d] = qa; sk[t * 65 + d] = ka; sv[t * 65 + d] = va;
  }
  __syncthreads();
  {
    int h = tid >> 6, q = (tid >> 3) & 7, k = tid & 7;
    float s = 0.f;
    for (int j = 0; j < 16; ++j)
      s += sq[q * 65 + h * 16 + j] * sk[k * 65 + h * 16 + j];
    satt[h][q][k] = s * 0.25f;
  }
  __syncthreads();
  if (tid < 32) {
    int h = tid >> 3, q2 = tid & 7;
    float m = -1e30f;
    for (int k2 = 0; k2 < 8; ++k2) m = fmaxf(m, satt[h][q2][k2]);
    float sum = 0.f;
    for (int k2 = 0; k2 < 8; ++k2) {
      float e = expf(satt[h][q2][k2] - m);
      satt[h][q2][k2] = e; sum += e;
    }
    float inv = 1.f / sum;
    for (int k2 = 0; k2 < 8; ++k2) satt[h][q2][k2] *= inv;
  }
  __syncthreads();
#pragma unroll
  for (int p = 0; p < 2; ++p) {
    int idx = p * 256 + tid, t = idx >> 6, d = idx & 63;
    int h = d >> 4;
    float o = 0.f;
    for (int k = 0; k < 8; ++k) o += satt[h][t][k] * sv[k * 65 + d];
    so2[t * 65 + d] = o;
  }
  __syncthreads();
  if (tid < 64) {
    float ob = 0.f;
    for (int t = 0; t < 8; ++t) ob += so2[t * 65 + tid];
    sob[tid] = ob * 0.125f;
  }
  __syncthreads();
  if (tid < 64) {
    float ctx = 0.f;
    for (int e = 0; e < 64; ++e) ctx += sob[e] * swo[tid * 65 + e];
    int spk = (ctx >= V_TH) ? 1 : 0;
    unsigned long long ball = __ballot(spk);
    if (tid < 2) {
      float lg = clsb[tid];
      for (int dd = 0; dd < 64; ++dd)
        if ((ball >> dd) & 1ull) lg += clsw[tid * 64 + dd];
      out[b * 2 + tid] = lg;
    }
    if (b == 0 && tid == 2)
      out[128] = 1.f - (float)(*cnt) / 16777216.f;
  }
}

extern "C" void kernel_launch(void* const* d_in, const int* in_sizes, int n_in,
                              void* d_out, int out_size, void* d_ws, size_t ws_size,
                              hipStream_t stream) {
  const float* x    = (const float*)d_in[0];
  const float* c1w  = (const float*)d_in[1];
  const float* c1b  = (const float*)d_in[2];
  const float* c2w  = (const float*)d_in[3];
  const float* c2b  = (const float*)d_in[4];
  const float* bt1  = (const float*)d_in[5];
  const float* bt2  = (const float*)d_in[6];
  const float* pw   = (const float*)d_in[7];
  const float* pb   = (const float*)d_in[8];
  const float* wq   = (const float*)d_in[9];
  const float* wk   = (const float*)d_in[10];
  const float* wv   = (const float*)d_in[11];
  const float* wo   = (const float*)d_in[12];
  const float* clsw = (const float*)d_in[13];
  const float* clsb = (const float*)d_in[14];
  float* out = (float*)d_out;

  uint8_t* ws = (uint8_t*)d_ws;
  uint64_t* trip  = (uint64_t*)(ws + OFF_TRIP);
  uint32_t* bits  = (uint32_t*)(ws + OFF_BITS);
  float*    pwt   = (float*)(ws + OFF_PWT);
  unsigned int* cnt = (unsigned int*)(ws + OFF_CNT);
  float*    tbl   = (float*)(ws + OFF_TBL);
  float*    part  = (float*)(ws + OFF_PART);

  k_mega1<<<1729, 256, 0, stream>>>(x, c1w, c1b, bt1, trip, pw, pwt, c2w, tbl, cnt);
  k_conv2_lif2<<<2048, 256, 0, stream>>>(trip, tbl, c2b, bt2, bits, cnt);
  k_proj_gemm<<<1024, 256, 0, stream>>>(bits, pwt, part);
  k_attn_final<<<64, 256, 0, stream>>>(part, pb, wq, wk, wv, wo, clsw, clsb, cnt, out);
}